// Round 3
// baseline (1196.615 us; speedup 1.0000x reference)
//
#include <hip/hip_runtime.h>
#include <hip/hip_bf16.h>
#include <math.h>

#define TOK 8192   // B*L
#define DM 512
#define NH 8
#define DKH 64
#define DFFN 2048
#define SEQ 1024
#define NBLK 4
#define NUMC 1000

typedef __attribute__((ext_vector_type(8))) short bf16x8;
typedef __attribute__((ext_vector_type(4))) float f32x4;
typedef __attribute__((ext_vector_type(4))) ushort u16x4;
typedef __hip_bfloat16 bf16;

__device__ __forceinline__ void gload_lds16(const ushort* g, ushort* l) {
    __builtin_amdgcn_global_load_lds(
        (const __attribute__((address_space(1))) void*)g,
        (__attribute__((address_space(3))) void*)l, 16, 0, 0);
}

// raw workgroup barrier WITHOUT the compiler's vmcnt(0)/lgkmcnt(0) drain;
// empty asm = compiler-level memory fence so LDS ops can't migrate across.
__device__ __forceinline__ void wgbar() {
    asm volatile("" ::: "memory");
    __builtin_amdgcn_s_barrier();
    asm volatile("" ::: "memory");
}

// ---------------------------------------------------------------- embed
__global__ __launch_bounds__(256) void embed_kernel(
    const int* __restrict__ q, const int* __restrict__ r,
    const float* __restrict__ ctx_emb, const float* __restrict__ val_emb,
    const float* __restrict__ pos_emb,
    float* __restrict__ ctx32, float* __restrict__ val32,
    bf16* __restrict__ ctx16, bf16* __restrict__ val16)
{
    const int t = blockIdx.x;
    const int inter = q[t] + NUMC * r[t];
    const int l = t & (SEQ - 1);
    const float* ce = ctx_emb + (size_t)inter * DM;
    const float* ve = val_emb + (size_t)inter * DM;
    const float* pe = pos_emb + (size_t)l * DM;
    const size_t o = (size_t)t * DM;
    for (int d = threadIdx.x; d < DM; d += 256) {
        float p = pe[d];
        float c = ce[d] + p;
        float v = ve[d] + p;
        ctx32[o + d] = c; val32[o + d] = v;
        ctx16[o + d] = __float2bfloat16(c);
        val16[o + d] = __float2bfloat16(v);
    }
}

// ---------------------------------------------------------------- transpose+cvt (weights)
__global__ __launch_bounds__(256) void transpose_kernel(
    const float* __restrict__ src, bf16* __restrict__ dst,
    int K, int N, long sb, long db)
{
    __shared__ float t[32][33];
    src += (long)blockIdx.z * sb;
    dst += (long)blockIdx.z * db;
    const int n0 = blockIdx.x * 32;
    const int k0 = blockIdx.y * 32;
    const int tx = threadIdx.x;
    const int ty = threadIdx.y;
    for (int i = ty; i < 32; i += 8) t[i][tx] = src[(size_t)(k0 + i) * N + n0 + tx];
    __syncthreads();
    for (int i = ty; i < 32; i += 8)
        dst[(size_t)(n0 + i) * K + k0 + tx] = __float2bfloat16(t[tx][i]);
}

// ---------------------------------------------------------------- MFMA GEMM (128-tile, R5 structure)
template<int BN, bool OUTBF16>
__global__ __launch_bounds__(256, 3) void mfma_gemm(
    const ushort* __restrict__ A, const ushort* __restrict__ Bt,
    const float* __restrict__ bias1, const float* __restrict__ bias2, int split,
    void* __restrict__ Cv, int N, int K, int relu, int vtmode,
    const ushort* __restrict__ A1, const ushort* __restrict__ Bt1,
    const float* __restrict__ bias1_1, void* __restrict__ Cv1)
{
    if (blockIdx.z) { A = A1; Bt = Bt1; bias1 = bias1_1; Cv = Cv1; }
    constexpr int MI = (BN == 128) ? 4 : 2;
    constexpr int BR = BN / 32;
    __shared__ ushort As[128 * 64];
    __shared__ ushort Bs[BN * 64];
    const int tid = threadIdx.x;
    const int wave = tid >> 6;
    const int lane = tid & 63;
    const int ln = lane & 15;
    const int kq = lane >> 4;
    const int nx = gridDim.x;
    const int lin = blockIdx.x + nx * blockIdx.y;
    const int loc = lin >> 3;
    const int mdiv = loc / nx;
    const int bm = ((lin & 7) + 8 * mdiv) * 128;
    const int bn = (loc - mdiv * nx) * BN;
    const int wr = (BN == 128) ? (wave >> 1) * 64 : wave * 32;
    const int wc = (BN == 128) ? (wave & 1) * 64 : 0;

    const int trow = tid >> 3;
    const int gcb = (tid & 7) ^ (trow & 7);
    const ushort* Ab = A + (size_t)(bm + trow) * K + gcb * 8;
    const ushort* Bb = Bt + (size_t)(bn + trow) * K + gcb * 8;
    ushort* AsW = As + wave * 512;
    ushort* BsW = Bs + wave * 512;

    f32x4 acc[MI][4];
#pragma unroll
    for (int i = 0; i < MI; ++i)
#pragma unroll
        for (int j = 0; j < 4; ++j) acc[i][j] = (f32x4){0.f, 0.f, 0.f, 0.f};

    for (int k0 = 0; k0 < K; k0 += 64) {
        __syncthreads();
#pragma unroll
        for (int p = 0; p < 4; ++p)
            gload_lds16(Ab + (size_t)32 * p * K + k0, AsW + p * 2048);
#pragma unroll
        for (int p = 0; p < BR; ++p)
            gload_lds16(Bb + (size_t)32 * p * K + k0, BsW + p * 2048);
        __syncthreads();
#pragma unroll
        for (int half = 0; half < 2; ++half) {
            const int cb = ((half * 4 + kq) ^ (ln & 7)) * 8;
            bf16x8 bfr[4];
#pragma unroll
            for (int j = 0; j < 4; ++j)
                bfr[j] = *(const bf16x8*)&Bs[(wc + j * 16 + ln) * 64 + cb];
#pragma unroll
            for (int i = 0; i < MI; ++i) {
                const bf16x8 af = *(const bf16x8*)&As[(wr + i * 16 + ln) * 64 + cb];
#pragma unroll
                for (int j = 0; j < 4; ++j)
                    acc[i][j] = __builtin_amdgcn_mfma_f32_16x16x32_bf16(af, bfr[j], acc[i][j], 0, 0, 0);
            }
        }
    }

#pragma unroll
    for (int i = 0; i < MI; ++i) {
        const int rowb = bm + wr + i * 16 + kq * 4;
#pragma unroll
        for (int j = 0; j < 4; ++j) {
            const int colg = bn + wc + j * 16 + ln;
            const float bv = (colg < split) ? bias1[colg] : bias2[colg - split];
            if (vtmode) {
                union { u16x4 v; ushort u[4]; } pk;
#pragma unroll
                for (int rr = 0; rr < 4; ++rr) {
                    float v = acc[i][j][rr] + bv;
                    bf16 t = __float2bfloat16(v);
                    pk.u[rr] = *(ushort*)&t;
                }
                *(u16x4*)((ushort*)Cv + ((size_t)(rowb >> 10) * 512 + colg) * 1024 + (rowb & 1023)) = pk.v;
            } else {
#pragma unroll
                for (int rr = 0; rr < 4; ++rr) {
                    float v = acc[i][j][rr] + bv;
                    if (relu) v = fmaxf(v, 0.f);
                    if (OUTBF16)
                        ((bf16*)Cv)[(size_t)(rowb + rr) * N + colg] = __float2bfloat16(v);
                    else
                        ((float*)Cv)[(size_t)(rowb + rr) * N + colg] = v;
                }
            }
        }
    }
}

// ---------------------------------------------------------------- MFMA GEMM 256x256, 8-wave,
// deep-slack per-phase pipeline (T2+T3+T4+T5). At 1 block/CU there is no TLP,
// so every staged chunk must be issued >= HBM-latency before its wait. Each
// chunk of tile t+1 is issued during tile t-1, right after its WAR-freeing
// phase in buffer b^1 (B free after ph0, A{0,2} after ph1, A{1,3} after ph3):
//   steady state, tile t: ph0 issues A{1,3}(t+1); ph1 issues B(t+2);
//   ph2 issues A{0,2}(t+2)  -> slack 6-7 phases for every chunk.
// Waits (per-wave vmcnt accounting, exact): vmcnt(12) end-ph1 publishes
// A{1,3}(t); vmcnt(8) end-ph3 publishes B(t+1)+A{0,2}(t+1). Tails use 8/2/0.
// K-accumulation order identical to the 128-tile kernel -> bit-identical C.
__global__ __launch_bounds__(512, 2) void mfma_gemm256(
    const ushort* __restrict__ A, const ushort* __restrict__ Bt,
    const float* __restrict__ bias, bf16* __restrict__ C, int N, int K, int relu,
    const ushort* __restrict__ A1, const ushort* __restrict__ Bt1,
    const float* __restrict__ bias1, bf16* __restrict__ C1)
{
    if (blockIdx.z) { A = A1; Bt = Bt1; bias = bias1; C = C1; }
    __shared__ ushort As[2 * 16384];   // [2 buf][256 rows][64 cols]
    __shared__ ushort Bs[2 * 16384];
    const int tid = threadIdx.x;
    const int wave = tid >> 6, lane = tid & 63;
    const int ln = lane & 15, kq = lane >> 4;
    const int wr = wave >> 2;          // 0..1  -> M offset wr*128
    const int wc = wave & 3;           // 0..3  -> N offset wc*64

    const int nx = gridDim.x;
    const int lin = blockIdx.x + nx * blockIdx.y;
    const int loc = lin >> 3;
    const int mdiv = loc / nx;
    const int bm = ((lin & 7) + 8 * mdiv) * 256;
    const int bn = (loc - mdiv * nx) * 256;

    const int srow = tid >> 3;                 // 0..63
    const int sgcb = (tid & 7) ^ (srow & 7);
    const ushort* Ag = A + (size_t)(bm + srow) * K + sgcb * 8;
    const ushort* Bg = Bt + (size_t)(bn + srow) * K + sgcb * 8;
    const int wofs = wave * 512;

#define STG_A(p, bb, kk) gload_lds16(Ag + (size_t)(64 * (p)) * K + (kk), As + (bb) * 16384 + (p) * 4096 + wofs)
#define STG_B(p, bb, kk) gload_lds16(Bg + (size_t)(64 * (p)) * K + (kk), Bs + (bb) * 16384 + (p) * 4096 + wofs)

// one compute phase: pre-barrier A-frag reads; barrier; lgkm0; 16 MFMA; WAIT; barrier
#define PH(q, WAITASM) { \
    bf16x8 af0[2], af1[2]; \
    _Pragma("unroll") \
    for (int h = 0; h < 2; ++h) { \
        const int cb = (((h * 4 + kq) ^ (ln & 7)) * 8); \
        af0[h] = *(const bf16x8*)&Asb[(wr * 128 + (2 * (q)) * 16 + ln) * 64 + cb]; \
        af1[h] = *(const bf16x8*)&Asb[(wr * 128 + (2 * (q) + 1) * 16 + ln) * 64 + cb]; \
    } \
    wgbar(); \
    asm volatile("s_waitcnt lgkmcnt(0)" ::: "memory"); \
    __builtin_amdgcn_s_setprio(1); \
    _Pragma("unroll") \
    for (int h = 0; h < 2; ++h) { \
        _Pragma("unroll") \
        for (int j = 0; j < 4; ++j) { \
            acc[2 * (q)][j]     = __builtin_amdgcn_mfma_f32_16x16x32_bf16(af0[h], bfr[j][h], acc[2 * (q)][j], 0, 0, 0); \
            acc[2 * (q) + 1][j] = __builtin_amdgcn_mfma_f32_16x16x32_bf16(af1[h], bfr[j][h], acc[2 * (q) + 1][j], 0, 0, 0); \
        } \
    } \
    __builtin_amdgcn_s_setprio(0); \
    WAITASM; \
    wgbar(); }

#define RD_BFR() \
    _Pragma("unroll") \
    for (int j = 0; j < 4; ++j) { \
        _Pragma("unroll") \
        for (int h = 0; h < 2; ++h) \
            bfr[j][h] = *(const bf16x8*)&Bsb[(wc * 64 + j * 16 + ln) * 64 + (((h * 4 + kq) ^ (ln & 7)) * 8)]; \
    }

    f32x4 acc[8][4];
#pragma unroll
    for (int i = 0; i < 8; ++i)
#pragma unroll
        for (int j = 0; j < 4; ++j) acc[i][j] = (f32x4){0.f, 0.f, 0.f, 0.f};

    const int NT = K >> 6;   // NT >= 3 required (callers: 8, 24)

    // prologue: issue in steady-state stream order so vmcnt counts are uniform:
    // B(0)x4, A02(0), A13(0), B(1)x4, A02(1); publish B(0)+A02(0) -> vmcnt(8)
    STG_B(0, 0, 0); STG_B(1, 0, 0); STG_B(2, 0, 0); STG_B(3, 0, 0);
    STG_A(0, 0, 0); STG_A(2, 0, 0);
    STG_A(1, 0, 0); STG_A(3, 0, 0);
    STG_B(0, 1, 64); STG_B(1, 1, 64); STG_B(2, 1, 64); STG_B(3, 1, 64);
    STG_A(0, 1, 64); STG_A(2, 1, 64);
    asm volatile("s_waitcnt vmcnt(8)" ::: "memory");
    wgbar();

    for (int t = 0; t < NT - 2; ++t) {
        const int b = t & 1;
        const int kn1 = (t + 1) << 6;
        const int kn2 = (t + 2) << 6;
        const ushort* Asb = As + b * 16384;
        const ushort* Bsb = Bs + b * 16384;
        bf16x8 bfr[4][2];
        // ph0: issue A{1,3}(t+1) -> buf b^1 (region free since ph3(t-1))
        STG_A(1, b ^ 1, kn1); STG_A(3, b ^ 1, kn1);
        RD_BFR();
        PH(0, )
        // ph1: issue B(t+2) -> buf b (B(t) frags fully read at ph0)
        STG_B(0, b, kn2); STG_B(1, b, kn2); STG_B(2, b, kn2); STG_B(3, b, kn2);
        PH(1, asm volatile("s_waitcnt vmcnt(12)" ::: "memory"))   // publishes A{1,3}(t)
        // ph2: issue A{0,2}(t+2) -> buf b (chunks 0,2 read at ph0-ph1)
        STG_A(0, b, kn2); STG_A(2, b, kn2);
        PH(2, )
        PH(3, asm volatile("s_waitcnt vmcnt(8)" ::: "memory"))    // publishes B(t+1)+A{0,2}(t+1)
    }
    {   // tile NT-2: only A{1,3}(NT-1) left to issue
        const int b = (NT - 2) & 1;
        const int kn1 = (NT - 1) << 6;
        const ushort* Asb = As + b * 16384;
        const ushort* Bsb = Bs + b * 16384;
        bf16x8 bfr[4][2];
        STG_A(1, b ^ 1, kn1); STG_A(3, b ^ 1, kn1);
        RD_BFR();
        PH(0, )
        PH(1, asm volatile("s_waitcnt vmcnt(8)" ::: "memory"))    // publishes A{1,3}(NT-2)
        PH(2, )
        PH(3, asm volatile("s_waitcnt vmcnt(2)" ::: "memory"))    // publishes B+A{0,2}(NT-1)
    }
    {   // tile NT-1: no staging
        const int b = (NT - 1) & 1;
        const ushort* Asb = As + b * 16384;
        const ushort* Bsb = Bs + b * 16384;
        bf16x8 bfr[4][2];
        RD_BFR();
        PH(0, )
        PH(1, asm volatile("s_waitcnt vmcnt(0)" ::: "memory"))    // publishes A{1,3}(NT-1)
        PH(2, )
        PH(3, )
    }
#undef PH
#undef RD_BFR
#undef STG_A
#undef STG_B

#pragma unroll
    for (int i = 0; i < 8; ++i) {
        const int gr = bm + wr * 128 + i * 16 + kq * 4;
#pragma unroll
        for (int j = 0; j < 4; ++j) {
            const int gc = bn + wc * 64 + j * 16 + ln;
            const float bv = bias[gc];
#pragma unroll
            for (int rr = 0; rr < 4; ++rr) {
                float v = acc[i][j][rr] + bv;
                if (relu) v = fmaxf(v, 0.f);
                C[(size_t)(gr + rr) * N + gc] = __float2bfloat16(v);
            }
        }
    }
}

// ---------------------------------------------------------------- MFMA flash attention
__global__ __launch_bounds__(256) void attn_kernel(
    const bf16* __restrict__ QK, const bf16* __restrict__ Vt,
    bf16* __restrict__ Og)
{
    __shared__ ushort Qs[64 * 64];
    __shared__ ushort Ks[64 * 64];
    __shared__ ushort Vs[64 * 64];      // [dim][key]
    __shared__ ushort Ps[4 * 16 * 68];  // per-wave P, padded (wave-private)

    const int tid = threadIdx.x;
    const int wave = tid >> 6, lane = tid & 63;
    const int ln = lane & 15, kq = lane >> 4;
    const int lin = blockIdx.x + 16 * blockIdx.y;
    const int loc = lin >> 3;
    const int qt = loc & 15;
    const int bh = (lin & 7) + 8 * (loc >> 4);
    const int b = bh >> 3, h = bh & 7;

    const int srow = tid >> 3;                 // 0..31
    const int sgcb = (tid & 7) ^ (srow & 7);
    const ushort* gQ = (const ushort*)QK + (size_t)(b * SEQ + qt * 64 + srow) * 1024 + h * 64 + sgcb * 8;
    const ushort* gK = (const ushort*)QK + (size_t)(b * SEQ + srow) * 1024 + 512 + h * 64 + sgcb * 8;
    const ushort* gV = (const ushort*)Vt + (size_t)(bh * 64 + srow) * 1024 + sgcb * 8;
    ushort* QsW = Qs + wave * 512;
    ushort* KsW = Ks + wave * 512;
    ushort* VsW = Vs + wave * 512;

    gload_lds16(gQ, QsW);
    gload_lds16(gQ + 32 * 1024, QsW + 2048);

    float rs[4];
    f32x4 oacc[4];
#pragma unroll
    for (int r = 0; r < 4; ++r) { rs[r] = 0.f; oacc[r] = (f32x4){0.f, 0.f, 0.f, 0.f}; }
    const float sc2 = 0.125f * 1.4426950408889634f;   // 1/sqrt(64) * log2(e)

    const int cb0 = (kq ^ (ln & 7)) * 8;
    const int cb1 = ((4 + kq) ^ (ln & 7)) * 8;

    for (int kt = 0; kt <= qt; ++kt) {
        __syncthreads();
        gload_lds16(gK + (size_t)kt * 64 * 1024, KsW);
        gload_lds16(gK + (size_t)(kt * 64 + 32) * 1024, KsW + 2048);
        gload_lds16(gV + kt * 64, VsW);
        gload_lds16(gV + 32 * 1024 + kt * 64, VsW + 2048);
        __syncthreads();

        const bf16x8 aq0 = *(const bf16x8*)&Qs[(wave * 16 + ln) * 64 + cb0];
        const bf16x8 aq1 = *(const bf16x8*)&Qs[(wave * 16 + ln) * 64 + cb1];
        f32x4 s[4];
#pragma unroll
        for (int c = 0; c < 4; ++c) {
            const bf16x8 bk0 = *(const bf16x8*)&Ks[(c * 16 + ln) * 64 + cb0];
            const bf16x8 bk1 = *(const bf16x8*)&Ks[(c * 16 + ln) * 64 + cb1];
            s[c] = (f32x4){0.f, 0.f, 0.f, 0.f};
            s[c] = __builtin_amdgcn_mfma_f32_16x16x32_bf16(aq0, bk0, s[c], 0, 0, 0);
            s[c] = __builtin_amdgcn_mfma_f32_16x16x32_bf16(aq1, bk1, s[c], 0, 0, 0);
        }
        if (kt == qt) {
#pragma unroll
            for (int c = 0; c < 4; ++c)
#pragma unroll
                for (int r = 0; r < 4; ++r) {
                    const int qg = wave * 16 + kq * 4 + r;
                    const int jg = c * 16 + ln;
                    const float pv = (jg <= qg) ? exp2f(s[c][r] * sc2) : 0.f;
                    rs[r] += pv;
                    *(bf16*)&Ps[wave * 1088 + (kq * 4 + r) * 68 + c * 16 + ln] = __float2bfloat16(pv);
                }
        } else {
#pragma unroll
            for (int c = 0; c < 4; ++c)
#pragma unroll
                for (int r = 0; r < 4; ++r) {
                    const float pv = exp2f(s[c][r] * sc2);
                    rs[r] += pv;
                    *(bf16*)&Ps[wave * 1088 + (kq * 4 + r) * 68 + c * 16 + ln] = __float2bfloat16(pv);
                }
        }
        const bf16x8 ap0 = *(const bf16x8*)&Ps[wave * 1088 + ln * 68 + kq * 8];
        const bf16x8 ap1 = *(const bf16x8*)&Ps[wave * 1088 + ln * 68 + 32 + kq * 8];
#pragma unroll
        for (int c2 = 0; c2 < 4; ++c2) {
            const bf16x8 bv0 = *(const bf16x8*)&Vs[(c2 * 16 + ln) * 64 + cb0];
            const bf16x8 bv1 = *(const bf16x8*)&Vs[(c2 * 16 + ln) * 64 + cb1];
            oacc[c2] = __builtin_amdgcn_mfma_f32_16x16x32_bf16(ap0, bv0, oacc[c2], 0, 0, 0);
            oacc[c2] = __builtin_amdgcn_mfma_f32_16x16x32_bf16(ap1, bv1, oacc[c2], 0, 0, 0);
        }
    }
    float inv[4];
#pragma unroll
    for (int r = 0; r < 4; ++r) {
        float v = rs[r];
        v += __shfl_xor(v, 1);
        v += __shfl_xor(v, 2);
        v += __shfl_xor(v, 4);
        v += __shfl_xor(v, 8);
        inv[r] = 1.f / v;
    }
#pragma unroll
    for (int c2 = 0; c2 < 4; ++c2)
#pragma unroll
        for (int r = 0; r < 4; ++r)
            Og[(size_t)(b * SEQ + qt * 64 + wave * 16 + kq * 4 + r) * 512 + h * 64 + c2 * 16 + ln]
                = __float2bfloat16(oacc[c2][r] * inv[r]);
}

// ---------------------------------------------------------------- layernorm pair
__global__ __launch_bounds__(256) void lnp_kernel(
    const float* __restrict__ x0, const bf16* __restrict__ r0, const float* __restrict__ s0,
    const float* __restrict__ b0, float* __restrict__ of0, bf16* __restrict__ oh0,
    const float* __restrict__ x1, const bf16* __restrict__ r1, const float* __restrict__ s1,
    const float* __restrict__ b1, float* __restrict__ of1, bf16* __restrict__ oh1)
{
    const float* x = x0; const bf16* res = r0; const float* s = s0; const float* bb = b0;
    float* of = of0; bf16* oh = oh0;
    if (blockIdx.y) { x = x1; res = r1; s = s1; bb = b1; of = of1; oh = oh1; }
    __shared__ float w1[4], w2[4];
    const size_t o = (size_t)blockIdx.x * DM;
    const int i0 = threadIdx.x, i1 = threadIdx.x + 256;
    const float v0 = x[o + i0] + __bfloat162float(res[o + i0]);
    const float v1 = x[o + i1] + __bfloat162float(res[o + i1]);
    float sum = v0 + v1;
#pragma unroll
    for (int off = 32; off; off >>= 1) sum += __shfl_down(sum, off);
    if ((threadIdx.x & 63) == 0) w1[threadIdx.x >> 6] = sum;
    __syncthreads();
    const float mu = (w1[0] + w1[1] + w1[2] + w1[3]) * (1.f / DM);
    const float d0 = v0 - mu, d1 = v1 - mu;
    float vs = d0 * d0 + d1 * d1;
#pragma unroll
    for (int off = 32; off; off >>= 1) vs += __shfl_down(vs, off);
    if ((threadIdx.x & 63) == 0) w2[threadIdx.x >> 6] = vs;
    __syncthreads();
    const float rstd = rsqrtf((w2[0] + w2[1] + w2[2] + w2[3]) * (1.f / DM) + 1e-5f);
    const float o0 = d0 * rstd * s[i0] + bb[i0];
    const float o1 = d1 * rstd * s[i1] + bb[i1];
    of[o + i0] = o0; of[o + i1] = o1;
    oh[o + i0] = __float2bfloat16(o0);
    oh[o + i1] = __float2bfloat16(o1);
}

// ---------------------------------------------------------------- head gather
__global__ __launch_bounds__(256) void gather_kernel(
    const bf16* __restrict__ ctx16, const bf16* __restrict__ val16,
    const float* __restrict__ skill, const int* __restrict__ q,
    bf16* __restrict__ feat)
{
    const int t = blockIdx.x;
    const float* sp = skill + (size_t)q[t] * DM;
    const bf16* cp = ctx16 + (size_t)t * DM;
    const bf16* vp = val16 + (size_t)t * DM;
    bf16* fp = feat + (size_t)t * (3 * DM);
    for (int d = threadIdx.x; d < DM; d += 256) {
        fp[d] = cp[d];
        fp[DM + d] = vp[d];
        fp[2 * DM + d] = __float2bfloat16(sp[d]);
    }
}

// ---------------------------------------------------------------- logits
__global__ __launch_bounds__(256) void logits_kernel(
    const float* __restrict__ h2, const float* __restrict__ w,
    const float* __restrict__ bptr, float* __restrict__ out)
{
    __shared__ float w1[4];
    const int t = blockIdx.x;
    float sum = h2[(size_t)t * 256 + threadIdx.x] * w[threadIdx.x];
#pragma unroll
    for (int off = 32; off; off >>= 1) sum += __shfl_down(sum, off);
    if ((threadIdx.x & 63) == 0) w1[threadIdx.x >> 6] = sum;
    __syncthreads();
    if (threadIdx.x == 0) {
        const float logit = w1[0] + w1[1] + w1[2] + w1[3] + bptr[0];
        out[t] = 1.f / (1.f + __expf(-logit));
    }
}

// ---------------------------------------------------------------- launch
extern "C" void kernel_launch(void* const* d_in, const int* in_sizes, int n_in,
                              void* d_out, int out_size, void* d_ws, size_t ws_size,
                              hipStream_t stream)
{
    const int*   q         = (const int*)d_in[0];
    const int*   r         = (const int*)d_in[1];
    const float* ctx_emb   = (const float*)d_in[2];
    const float* val_emb   = (const float*)d_in[3];
    const float* skill_emb = (const float*)d_in[4];
    const float* pos_emb   = (const float*)d_in[5];
    const float* Wq = (const float*)d_in[6];
    const float* bq = (const float*)d_in[7];
    const float* Wk = (const float*)d_in[8];
    const float* bk = (const float*)d_in[9];
    const float* Wv = (const float*)d_in[10];
    const float* bv = (const float*)d_in[11];
    const float* Wo = (const float*)d_in[12];
    const float* bo = (const float*)d_in[13];
    const float* ln1c_s = (const float*)d_in[14];
    const float* ln1c_b = (const float*)d_in[15];
    const float* ln1v_s = (const float*)d_in[16];
    const float* ln1v_b = (const float*)d_in[17];
    const float* ln2c_s = (const float*)d_in[18];
    const float* ln2c_b = (const float*)d_in[19];
    const float* ln2v_s = (const float*)d_in[20];
    const float* ln2v_b = (const float*)d_in[21];
    const float* fc1c_W = (const float*)d_in[22];
    const float* fc1c_b = (const float*)d_in[23];
    const float* fc2c_W = (const float*)d_in[24];
    const float* fc2c_b = (const float*)d_in[25];
    const float* fc1v_W = (const float*)d_in[26];
    const float* fc1v_b = (const float*)d_in[27];
    const float* fc2v_W = (const float*)d_in[28];
    const float* fc2v_b = (const float*)d_in[29];
    const float* hW1 = (const float*)d_in[30];
    const float* hb1 = (const float*)d_in[31];
    const float* hW2 = (const float*)d_in[32];
    const float* hb2 = (const float*)d_in[33];
    const float* hW3 = (const float*)d_in[34];
    const float* hb3 = (const float*)d_in[35];
    float* out = (float*)d_out;

    char* p = (char*)d_ws;
    auto alloc = [&](size_t bytes) { char* ret = p; p += bytes; return ret; };
    float* ctx32 = (float*)alloc(16777216);
    float* val32 = (float*)alloc(16777216);
    bf16*  ob16c = (bf16*)alloc(8388608);
    bf16*  ob16v = (bf16*)alloc(8388608);
    bf16*  ctx16 = (bf16*)alloc(8388608);
    bf16*  val16 = (bf16*)alloc(8388608);
    bf16*  qk16  = (bf16*)alloc(16777216);   // A: [8192][1024]
    bf16*  v16pad= (bf16*)alloc(8388608);    // B: dead (alias sizing)
    bf16*  vt16  = (bf16*)alloc(8388608);    // C: [(b*8+h)*64+d][1024]
    bf16*  att16 = (bf16*)alloc(8388608);    // D
    bf16*  mid16c = (bf16*)alloc(33554432);  // [8192][2048]
    bf16*  qkT   = (bf16*)alloc(4194304);
    bf16*  vT    = (bf16*)alloc(2097152);
    bf16*  oT    = (bf16*)alloc(2097152);
    bf16*  fc1cT = (bf16*)alloc(8388608);
    bf16*  fc2cT = (bf16*)alloc(8388608);
    bf16*  fc1vT = (bf16*)alloc(8388608);
    bf16*  fc2vT = (bf16*)alloc(8388608);
    bf16*  hW1T  = (bf16*)alloc(6291456);
    bf16*  hW2T  = (bf16*)alloc(1048576);
    (void)v16pad;
    // aliases (liveness-checked):
    bf16*  mid16v = qk16;                    // dead during FFN
    bf16*  feat16 = qk16;                    // post-loop
    float* h2     = (float*)vt16;            // post-loop

    const dim3 tb(32, 8);
    transpose_kernel<<<dim3(16, 16, 4), tb, 0, stream>>>(Wq, qkT,          512, 512, 262144, 524288);
    transpose_kernel<<<dim3(16, 16, 4), tb, 0, stream>>>(Wk, qkT + 262144, 512, 512, 262144, 524288);
    transpose_kernel<<<dim3(16, 16, 4), tb, 0, stream>>>(Wv, vT, 512, 512, 262144, 262144);
    transpose_kernel<<<dim3(16, 16, 4), tb, 0, stream>>>(Wo, oT, 512, 512, 262144, 262144);
    transpose_kernel<<<dim3(64, 16, 4), tb, 0, stream>>>(fc1c_W, fc1cT, 512, 2048, 1048576, 1048576);
    transpose_kernel<<<dim3(16, 64, 4), tb, 0, stream>>>(fc2c_W, fc2cT, 2048, 512, 1048576, 1048576);
    transpose_kernel<<<dim3(64, 16, 4), tb, 0, stream>>>(fc1v_W, fc1vT, 512, 2048, 1048576, 1048576);
    transpose_kernel<<<dim3(16, 64, 4), tb, 0, stream>>>(fc2v_W, fc2vT, 2048, 512, 1048576, 1048576);
    transpose_kernel<<<dim3(64, 48, 1), tb, 0, stream>>>(hW1, hW1T, 1536, 2048, 0, 0);
    transpose_kernel<<<dim3(8, 64, 1),  tb, 0, stream>>>(hW2, hW2T, 2048, 256, 0, 0);

    embed_kernel<<<TOK, 256, 0, stream>>>(q, r, ctx_emb, val_emb, pos_emb,
                                          ctx32, val32, ctx16, val16);

    for (int i = 0; i < NBLK; ++i) {
        mfma_gemm<128, true><<<dim3(8, 64), 256, 0, stream>>>(
            (const ushort*)ctx16, (const ushort*)(qkT + (size_t)i * 524288),
            bq + i * DM, bk + i * DM, 512, qk16, 1024, 512, 0, 0,
            nullptr, nullptr, nullptr, nullptr);
        mfma_gemm<64, true><<<dim3(8, 64), 256, 0, stream>>>(
            (const ushort*)val16, (const ushort*)(vT + (size_t)i * 262144),
            bv + i * DM, nullptr, 1 << 30, vt16, 512, 512, 0, 1,
            nullptr, nullptr, nullptr, nullptr);
        attn_kernel<<<dim3(16, 64), 256, 0, stream>>>(qk16, vt16, att16);
        mfma_gemm<64, true><<<dim3(8, 64), 256, 0, stream>>>(
            (const ushort*)att16, (const ushort*)(oT + (size_t)i * 262144),
            bo + i * DM, nullptr, 1 << 30, ob16c, 512, 512, 0, 0,
            nullptr, nullptr, nullptr, nullptr);
        lnp_kernel<<<dim3(TOK, 2), 256, 0, stream>>>(
            ctx32, ob16c, ln1c_s + i * DM, ln1c_b + i * DM, ctx32, ctx16,
            val32, ob16c, ln1v_s + i * DM, ln1v_b + i * DM, val32, val16);
        mfma_gemm256<<<dim3(8, 32, 2), 512, 0, stream>>>(
            (const ushort*)ctx16, (const ushort*)(fc1cT + (size_t)i * 1048576),
            fc1c_b + i * DFFN, mid16c, 2048, 512, 1,
            (const ushort*)val16, (const ushort*)(fc1vT + (size_t)i * 1048576),
            fc1v_b + i * DFFN, mid16v);
        mfma_gemm<128, true><<<dim3(4, 64, 2), 256, 0, stream>>>(
            (const ushort*)mid16c, (const ushort*)(fc2cT + (size_t)i * 1048576),
            fc2c_b + i * DM, nullptr, 1 << 30, ob16c, 512, 2048, 0, 0,
            (const ushort*)mid16v, (const ushort*)(fc2vT + (size_t)i * 1048576),
            fc2v_b + i * DM, ob16v);
        lnp_kernel<<<dim3(TOK, 2), 256, 0, stream>>>(
            ctx32, ob16c, ln2c_s + i * DM, ln2c_b + i * DM, ctx32, ctx16,
            val32, ob16v, ln2v_s + i * DM, ln2v_b + i * DM, val32, val16);
    }

    gather_kernel<<<TOK, 256, 0, stream>>>(ctx16, val16, skill_emb, q, feat16);
    mfma_gemm256<<<dim3(8, 32), 512, 0, stream>>>(
        (const ushort*)feat16, (const ushort*)hW1T, hb1, mid16c, 2048, 1536, 1,
        nullptr, nullptr, nullptr, nullptr);
    mfma_gemm<64, false><<<dim3(4, 64), 256, 0, stream>>>(
        (const ushort*)mid16c, (const ushort*)hW2T, hb2, nullptr, 1 << 30, h2, 256, 2048, 1, 0,
        nullptr, nullptr, nullptr, nullptr);
    logits_kernel<<<TOK, 256, 0, stream>>>(h2, hW3, hb3, out);
}

// Round 4
// 1154.040 us; speedup vs baseline: 1.0369x; 1.0369x over previous
//
#include <hip/hip_runtime.h>
#include <hip/hip_bf16.h>
#include <math.h>

#define TOK 8192   // B*L
#define DM 512
#define NH 8
#define DKH 64
#define DFFN 2048
#define SEQ 1024
#define NBLK 4
#define NUMC 1000

typedef __attribute__((ext_vector_type(8))) short bf16x8;
typedef __attribute__((ext_vector_type(4))) float f32x4;
typedef __attribute__((ext_vector_type(4))) ushort u16x4;
typedef __hip_bfloat16 bf16;

__device__ __forceinline__ void gload_lds16(const ushort* g, ushort* l) {
    __builtin_amdgcn_global_load_lds(
        (const __attribute__((address_space(1))) void*)g,
        (__attribute__((address_space(3))) void*)l, 16, 0, 0);
}

// raw workgroup barrier WITHOUT the compiler's vmcnt(0)/lgkmcnt(0) drain;
// empty asm = compiler-level memory fence so LDS ops can't migrate across.
__device__ __forceinline__ void wgbar() {
    asm volatile("" ::: "memory");
    __builtin_amdgcn_s_barrier();
    asm volatile("" ::: "memory");
}

// ---------------------------------------------------------------- embed
__global__ __launch_bounds__(256) void embed_kernel(
    const int* __restrict__ q, const int* __restrict__ r,
    const float* __restrict__ ctx_emb, const float* __restrict__ val_emb,
    const float* __restrict__ pos_emb,
    float* __restrict__ ctx32, float* __restrict__ val32,
    bf16* __restrict__ ctx16, bf16* __restrict__ val16)
{
    const int t = blockIdx.x;
    const int inter = q[t] + NUMC * r[t];
    const int l = t & (SEQ - 1);
    const float* ce = ctx_emb + (size_t)inter * DM;
    const float* ve = val_emb + (size_t)inter * DM;
    const float* pe = pos_emb + (size_t)l * DM;
    const size_t o = (size_t)t * DM;
    for (int d = threadIdx.x; d < DM; d += 256) {
        float p = pe[d];
        float c = ce[d] + p;
        float v = ve[d] + p;
        ctx32[o + d] = c; val32[o + d] = v;
        ctx16[o + d] = __float2bfloat16(c);
        val16[o + d] = __float2bfloat16(v);
    }
}

// ---------------------------------------------------------------- transpose+cvt (weights)
__global__ __launch_bounds__(256) void transpose_kernel(
    const float* __restrict__ src, bf16* __restrict__ dst,
    int K, int N, long sb, long db)
{
    __shared__ float t[32][33];
    src += (long)blockIdx.z * sb;
    dst += (long)blockIdx.z * db;
    const int n0 = blockIdx.x * 32;
    const int k0 = blockIdx.y * 32;
    const int tx = threadIdx.x;
    const int ty = threadIdx.y;
    for (int i = ty; i < 32; i += 8) t[i][tx] = src[(size_t)(k0 + i) * N + n0 + tx];
    __syncthreads();
    for (int i = ty; i < 32; i += 8)
        dst[(size_t)(n0 + i) * K + k0 + tx] = __float2bfloat16(t[tx][i]);
}

// ---------------------------------------------------------------- MFMA GEMM (128-tile, R5 structure)
template<int BN, bool OUTBF16>
__global__ __launch_bounds__(256, 3) void mfma_gemm(
    const ushort* __restrict__ A, const ushort* __restrict__ Bt,
    const float* __restrict__ bias1, const float* __restrict__ bias2, int split,
    void* __restrict__ Cv, int N, int K, int relu, int vtmode,
    const ushort* __restrict__ A1, const ushort* __restrict__ Bt1,
    const float* __restrict__ bias1_1, void* __restrict__ Cv1)
{
    if (blockIdx.z) { A = A1; Bt = Bt1; bias1 = bias1_1; Cv = Cv1; }
    constexpr int MI = (BN == 128) ? 4 : 2;
    constexpr int BR = BN / 32;
    __shared__ ushort As[128 * 64];
    __shared__ ushort Bs[BN * 64];
    const int tid = threadIdx.x;
    const int wave = tid >> 6;
    const int lane = tid & 63;
    const int ln = lane & 15;
    const int kq = lane >> 4;
    const int nx = gridDim.x;
    const int lin = blockIdx.x + nx * blockIdx.y;
    const int loc = lin >> 3;
    const int mdiv = loc / nx;
    const int bm = ((lin & 7) + 8 * mdiv) * 128;
    const int bn = (loc - mdiv * nx) * BN;
    const int wr = (BN == 128) ? (wave >> 1) * 64 : wave * 32;
    const int wc = (BN == 128) ? (wave & 1) * 64 : 0;

    const int trow = tid >> 3;
    const int gcb = (tid & 7) ^ (trow & 7);
    const ushort* Ab = A + (size_t)(bm + trow) * K + gcb * 8;
    const ushort* Bb = Bt + (size_t)(bn + trow) * K + gcb * 8;
    ushort* AsW = As + wave * 512;
    ushort* BsW = Bs + wave * 512;

    f32x4 acc[MI][4];
#pragma unroll
    for (int i = 0; i < MI; ++i)
#pragma unroll
        for (int j = 0; j < 4; ++j) acc[i][j] = (f32x4){0.f, 0.f, 0.f, 0.f};

    for (int k0 = 0; k0 < K; k0 += 64) {
        __syncthreads();
#pragma unroll
        for (int p = 0; p < 4; ++p)
            gload_lds16(Ab + (size_t)32 * p * K + k0, AsW + p * 2048);
#pragma unroll
        for (int p = 0; p < BR; ++p)
            gload_lds16(Bb + (size_t)32 * p * K + k0, BsW + p * 2048);
        __syncthreads();
#pragma unroll
        for (int half = 0; half < 2; ++half) {
            const int cb = ((half * 4 + kq) ^ (ln & 7)) * 8;
            bf16x8 bfr[4];
#pragma unroll
            for (int j = 0; j < 4; ++j)
                bfr[j] = *(const bf16x8*)&Bs[(wc + j * 16 + ln) * 64 + cb];
#pragma unroll
            for (int i = 0; i < MI; ++i) {
                const bf16x8 af = *(const bf16x8*)&As[(wr + i * 16 + ln) * 64 + cb];
#pragma unroll
                for (int j = 0; j < 4; ++j)
                    acc[i][j] = __builtin_amdgcn_mfma_f32_16x16x32_bf16(af, bfr[j], acc[i][j], 0, 0, 0);
            }
        }
    }

#pragma unroll
    for (int i = 0; i < MI; ++i) {
        const int rowb = bm + wr + i * 16 + kq * 4;
#pragma unroll
        for (int j = 0; j < 4; ++j) {
            const int colg = bn + wc + j * 16 + ln;
            const float bv = (colg < split) ? bias1[colg] : bias2[colg - split];
            if (vtmode) {
                union { u16x4 v; ushort u[4]; } pk;
#pragma unroll
                for (int rr = 0; rr < 4; ++rr) {
                    float v = acc[i][j][rr] + bv;
                    bf16 t = __float2bfloat16(v);
                    pk.u[rr] = *(ushort*)&t;
                }
                *(u16x4*)((ushort*)Cv + ((size_t)(rowb >> 10) * 512 + colg) * 1024 + (rowb & 1023)) = pk.v;
            } else {
#pragma unroll
                for (int rr = 0; rr < 4; ++rr) {
                    float v = acc[i][j][rr] + bv;
                    if (relu) v = fmaxf(v, 0.f);
                    if (OUTBF16)
                        ((bf16*)Cv)[(size_t)(rowb + rr) * N + colg] = __float2bfloat16(v);
                    else
                        ((float*)Cv)[(size_t)(rowb + rr) * N + colg] = v;
                }
            }
        }
    }
}

// ---------------------------------------------------------------- MFMA flash attention
// Double-buffered K/V staging with counted vmcnt (minimum 2-phase T3/T4):
//   per kt: wgbar (WAR: all waves done reading buf b^1) -> issue kt+1's 4
//   gloads into b^1 -> s_waitcnt vmcnt(4) (kt's loads, issued one full
//   compute-phase earlier, have landed; kt+1's stay in flight) -> wgbar
//   (publish) -> compute on buf b. Never drains to 0 except the last tile.
// Per-wave vmcnt accounting: Q(2 loads, drained at kt=0 by vmcnt(4) since
// they're oldest) + 4 loads per stage. Compute identical to single-buffer
// version -> bit-identical output.
__global__ __launch_bounds__(256) void attn_kernel(
    const bf16* __restrict__ QK, const bf16* __restrict__ Vt,
    bf16* __restrict__ Og)
{
    __shared__ ushort Qs[64 * 64];
    __shared__ ushort Ks[2][64 * 64];
    __shared__ ushort Vs[2][64 * 64];   // [dim][key]
    __shared__ ushort Ps[4 * 16 * 68];  // per-wave P, padded (wave-private)

    const int tid = threadIdx.x;
    const int wave = tid >> 6, lane = tid & 63;
    const int ln = lane & 15, kq = lane >> 4;
    const int lin = blockIdx.x + 16 * blockIdx.y;
    const int loc = lin >> 3;
    const int qt = loc & 15;
    const int bh = (lin & 7) + 8 * (loc >> 4);
    const int b = bh >> 3, h = bh & 7;

    const int srow = tid >> 3;                 // 0..31
    const int sgcb = (tid & 7) ^ (srow & 7);
    const ushort* gQ = (const ushort*)QK + (size_t)(b * SEQ + qt * 64 + srow) * 1024 + h * 64 + sgcb * 8;
    const ushort* gK = (const ushort*)QK + (size_t)(b * SEQ + srow) * 1024 + 512 + h * 64 + sgcb * 8;
    const ushort* gV = (const ushort*)Vt + (size_t)(bh * 64 + srow) * 1024 + sgcb * 8;
    ushort* QsW = Qs + wave * 512;

    gload_lds16(gQ, QsW);
    gload_lds16(gQ + 32 * 1024, QsW + 2048);

    // stage kt=0 into buf 0
    {
        gload_lds16(gK, Ks[0] + wave * 512);
        gload_lds16(gK + (size_t)32 * 1024, Ks[0] + 2048 + wave * 512);
        gload_lds16(gV, Vs[0] + wave * 512);
        gload_lds16(gV + (size_t)32 * 1024, Vs[0] + 2048 + wave * 512);
    }

    float rs[4];
    f32x4 oacc[4];
#pragma unroll
    for (int r = 0; r < 4; ++r) { rs[r] = 0.f; oacc[r] = (f32x4){0.f, 0.f, 0.f, 0.f}; }
    const float sc2 = 0.125f * 1.4426950408889634f;   // 1/sqrt(64) * log2(e)

    const int cb0 = (kq ^ (ln & 7)) * 8;
    const int cb1 = ((4 + kq) ^ (ln & 7)) * 8;

    for (int kt = 0; kt <= qt; ++kt) {
        const int bf = kt & 1;
        wgbar();   // WAR: all waves finished reading buf bf^1 (iter kt-1)
        if (kt < qt) {
            const size_t kn = (size_t)(kt + 1) * 64;
            gload_lds16(gK + kn * 1024, Ks[bf ^ 1] + wave * 512);
            gload_lds16(gK + (kn + 32) * 1024, Ks[bf ^ 1] + 2048 + wave * 512);
            gload_lds16(gV + kn, Vs[bf ^ 1] + wave * 512);
            gload_lds16(gV + (size_t)32 * 1024 + kn, Vs[bf ^ 1] + 2048 + wave * 512);
            asm volatile("s_waitcnt vmcnt(4)" ::: "memory");  // kt landed (+Q at kt=0)
        } else {
            asm volatile("s_waitcnt vmcnt(0)" ::: "memory");
        }
        wgbar();   // publish buf bf

        // S = Q K^T : per wave 16x64
        const bf16x8 aq0 = *(const bf16x8*)&Qs[(wave * 16 + ln) * 64 + cb0];
        const bf16x8 aq1 = *(const bf16x8*)&Qs[(wave * 16 + ln) * 64 + cb1];
        f32x4 s[4];
        __builtin_amdgcn_s_setprio(1);
#pragma unroll
        for (int c = 0; c < 4; ++c) {
            const bf16x8 bk0 = *(const bf16x8*)&Ks[bf][(c * 16 + ln) * 64 + cb0];
            const bf16x8 bk1 = *(const bf16x8*)&Ks[bf][(c * 16 + ln) * 64 + cb1];
            s[c] = (f32x4){0.f, 0.f, 0.f, 0.f};
            s[c] = __builtin_amdgcn_mfma_f32_16x16x32_bf16(aq0, bk0, s[c], 0, 0, 0);
            s[c] = __builtin_amdgcn_mfma_f32_16x16x32_bf16(aq1, bk1, s[c], 0, 0, 0);
        }
        __builtin_amdgcn_s_setprio(0);
        // P = exp2(s*sc2) with causal mask on the diagonal tile; no max shift
        if (kt == qt) {
#pragma unroll
            for (int c = 0; c < 4; ++c)
#pragma unroll
                for (int r = 0; r < 4; ++r) {
                    const int qg = wave * 16 + kq * 4 + r;
                    const int jg = c * 16 + ln;
                    const float pv = (jg <= qg) ? exp2f(s[c][r] * sc2) : 0.f;
                    rs[r] += pv;
                    *(bf16*)&Ps[wave * 1088 + (kq * 4 + r) * 68 + c * 16 + ln] = __float2bfloat16(pv);
                }
        } else {
#pragma unroll
            for (int c = 0; c < 4; ++c)
#pragma unroll
                for (int r = 0; r < 4; ++r) {
                    const float pv = exp2f(s[c][r] * sc2);
                    rs[r] += pv;
                    *(bf16*)&Ps[wave * 1088 + (kq * 4 + r) * 68 + c * 16 + ln] = __float2bfloat16(pv);
                }
        }
        // P V (P back from LDS in A-layout; same-wave RAW)
        const bf16x8 ap0 = *(const bf16x8*)&Ps[wave * 1088 + ln * 68 + kq * 8];
        const bf16x8 ap1 = *(const bf16x8*)&Ps[wave * 1088 + ln * 68 + 32 + kq * 8];
        __builtin_amdgcn_s_setprio(1);
#pragma unroll
        for (int c2 = 0; c2 < 4; ++c2) {
            const bf16x8 bv0 = *(const bf16x8*)&Vs[bf][(c2 * 16 + ln) * 64 + cb0];
            const bf16x8 bv1 = *(const bf16x8*)&Vs[bf][(c2 * 16 + ln) * 64 + cb1];
            oacc[c2] = __builtin_amdgcn_mfma_f32_16x16x32_bf16(ap0, bv0, oacc[c2], 0, 0, 0);
            oacc[c2] = __builtin_amdgcn_mfma_f32_16x16x32_bf16(ap1, bv1, oacc[c2], 0, 0, 0);
        }
        __builtin_amdgcn_s_setprio(0);
    }
    // single row-sum reduction at the end
    float inv[4];
#pragma unroll
    for (int r = 0; r < 4; ++r) {
        float v = rs[r];
        v += __shfl_xor(v, 1);
        v += __shfl_xor(v, 2);
        v += __shfl_xor(v, 4);
        v += __shfl_xor(v, 8);
        inv[r] = 1.f / v;
    }
#pragma unroll
    for (int c2 = 0; c2 < 4; ++c2)
#pragma unroll
        for (int r = 0; r < 4; ++r)
            Og[(size_t)(b * SEQ + qt * 64 + wave * 16 + kq * 4 + r) * 512 + h * 64 + c2 * 16 + ln]
                = __float2bfloat16(oacc[c2][r] * inv[r]);
}

// ---------------------------------------------------------------- layernorm pair
__global__ __launch_bounds__(256) void lnp_kernel(
    const float* __restrict__ x0, const bf16* __restrict__ r0, const float* __restrict__ s0,
    const float* __restrict__ b0, float* __restrict__ of0, bf16* __restrict__ oh0,
    const float* __restrict__ x1, const bf16* __restrict__ r1, const float* __restrict__ s1,
    const float* __restrict__ b1, float* __restrict__ of1, bf16* __restrict__ oh1)
{
    const float* x = x0; const bf16* res = r0; const float* s = s0; const float* bb = b0;
    float* of = of0; bf16* oh = oh0;
    if (blockIdx.y) { x = x1; res = r1; s = s1; bb = b1; of = of1; oh = oh1; }
    __shared__ float w1[4], w2[4];
    const size_t o = (size_t)blockIdx.x * DM;
    const int i0 = threadIdx.x, i1 = threadIdx.x + 256;
    const float v0 = x[o + i0] + __bfloat162float(res[o + i0]);
    const float v1 = x[o + i1] + __bfloat162float(res[o + i1]);
    float sum = v0 + v1;
#pragma unroll
    for (int off = 32; off; off >>= 1) sum += __shfl_down(sum, off);
    if ((threadIdx.x & 63) == 0) w1[threadIdx.x >> 6] = sum;
    __syncthreads();
    const float mu = (w1[0] + w1[1] + w1[2] + w1[3]) * (1.f / DM);
    const float d0 = v0 - mu, d1 = v1 - mu;
    float vs = d0 * d0 + d1 * d1;
#pragma unroll
    for (int off = 32; off; off >>= 1) vs += __shfl_down(vs, off);
    if ((threadIdx.x & 63) == 0) w2[threadIdx.x >> 6] = vs;
    __syncthreads();
    const float rstd = rsqrtf((w2[0] + w2[1] + w2[2] + w2[3]) * (1.f / DM) + 1e-5f);
    const float o0 = d0 * rstd * s[i0] + bb[i0];
    const float o1 = d1 * rstd * s[i1] + bb[i1];
    of[o + i0] = o0; of[o + i1] = o1;
    oh[o + i0] = __float2bfloat16(o0);
    oh[o + i1] = __float2bfloat16(o1);
}

// ---------------------------------------------------------------- head gather
__global__ __launch_bounds__(256) void gather_kernel(
    const bf16* __restrict__ ctx16, const bf16* __restrict__ val16,
    const float* __restrict__ skill, const int* __restrict__ q,
    bf16* __restrict__ feat)
{
    const int t = blockIdx.x;
    const float* sp = skill + (size_t)q[t] * DM;
    const bf16* cp = ctx16 + (size_t)t * DM;
    const bf16* vp = val16 + (size_t)t * DM;
    bf16* fp = feat + (size_t)t * (3 * DM);
    for (int d = threadIdx.x; d < DM; d += 256) {
        fp[d] = cp[d];
        fp[DM + d] = vp[d];
        fp[2 * DM + d] = __float2bfloat16(sp[d]);
    }
}

// ---------------------------------------------------------------- logits
__global__ __launch_bounds__(256) void logits_kernel(
    const float* __restrict__ h2, const float* __restrict__ w,
    const float* __restrict__ bptr, float* __restrict__ out)
{
    __shared__ float w1[4];
    const int t = blockIdx.x;
    float sum = h2[(size_t)t * 256 + threadIdx.x] * w[threadIdx.x];
#pragma unroll
    for (int off = 32; off; off >>= 1) sum += __shfl_down(sum, off);
    if ((threadIdx.x & 63) == 0) w1[threadIdx.x >> 6] = sum;
    __syncthreads();
    if (threadIdx.x == 0) {
        const float logit = w1[0] + w1[1] + w1[2] + w1[3] + bptr[0];
        out[t] = 1.f / (1.f + __expf(-logit));
    }
}

// ---------------------------------------------------------------- launch
extern "C" void kernel_launch(void* const* d_in, const int* in_sizes, int n_in,
                              void* d_out, int out_size, void* d_ws, size_t ws_size,
                              hipStream_t stream)
{
    const int*   q         = (const int*)d_in[0];
    const int*   r         = (const int*)d_in[1];
    const float* ctx_emb   = (const float*)d_in[2];
    const float* val_emb   = (const float*)d_in[3];
    const float* skill_emb = (const float*)d_in[4];
    const float* pos_emb   = (const float*)d_in[5];
    const float* Wq = (const float*)d_in[6];
    const float* bq = (const float*)d_in[7];
    const float* Wk = (const float*)d_in[8];
    const float* bk = (const float*)d_in[9];
    const float* Wv = (const float*)d_in[10];
    const float* bv = (const float*)d_in[11];
    const float* Wo = (const float*)d_in[12];
    const float* bo = (const float*)d_in[13];
    const float* ln1c_s = (const float*)d_in[14];
    const float* ln1c_b = (const float*)d_in[15];
    const float* ln1v_s = (const float*)d_in[16];
    const float* ln1v_b = (const float*)d_in[17];
    const float* ln2c_s = (const float*)d_in[18];
    const float* ln2c_b = (const float*)d_in[19];
    const float* ln2v_s = (const float*)d_in[20];
    const float* ln2v_b = (const float*)d_in[21];
    const float* fc1c_W = (const float*)d_in[22];
    const float* fc1c_b = (const float*)d_in[23];
    const float* fc2c_W = (const float*)d_in[24];
    const float* fc2c_b = (const float*)d_in[25];
    const float* fc1v_W = (const float*)d_in[26];
    const float* fc1v_b = (const float*)d_in[27];
    const float* fc2v_W = (const float*)d_in[28];
    const float* fc2v_b = (const float*)d_in[29];
    const float* hW1 = (const float*)d_in[30];
    const float* hb1 = (const float*)d_in[31];
    const float* hW2 = (const float*)d_in[32];
    const float* hb2 = (const float*)d_in[33];
    const float* hW3 = (const float*)d_in[34];
    const float* hb3 = (const float*)d_in[35];
    float* out = (float*)d_out;

    char* p = (char*)d_ws;
    auto alloc = [&](size_t bytes) { char* ret = p; p += bytes; return ret; };
    float* ctx32 = (float*)alloc(16777216);
    float* val32 = (float*)alloc(16777216);
    bf16*  ob16c = (bf16*)alloc(8388608);
    bf16*  ob16v = (bf16*)alloc(8388608);
    bf16*  ctx16 = (bf16*)alloc(8388608);
    bf16*  val16 = (bf16*)alloc(8388608);
    bf16*  qk16  = (bf16*)alloc(16777216);   // A: [8192][1024]
    bf16*  v16pad= (bf16*)alloc(8388608);    // B: dead (alias sizing)
    bf16*  vt16  = (bf16*)alloc(8388608);    // C: [(b*8+h)*64+d][1024]
    bf16*  att16 = (bf16*)alloc(8388608);    // D
    bf16*  mid16c = (bf16*)alloc(33554432);  // [8192][2048]
    bf16*  qkT   = (bf16*)alloc(4194304);
    bf16*  vT    = (bf16*)alloc(2097152);
    bf16*  oT    = (bf16*)alloc(2097152);
    bf16*  fc1cT = (bf16*)alloc(8388608);
    bf16*  fc2cT = (bf16*)alloc(8388608);
    bf16*  fc1vT = (bf16*)alloc(8388608);
    bf16*  fc2vT = (bf16*)alloc(8388608);
    bf16*  hW1T  = (bf16*)alloc(6291456);
    bf16*  hW2T  = (bf16*)alloc(1048576);
    (void)v16pad;
    // aliases (liveness-checked):
    bf16*  mid16v = qk16;                    // dead during FFN
    bf16*  feat16 = qk16;                    // post-loop
    float* h2     = (float*)vt16;            // post-loop

    const dim3 tb(32, 8);
    transpose_kernel<<<dim3(16, 16, 4), tb, 0, stream>>>(Wq, qkT,          512, 512, 262144, 524288);
    transpose_kernel<<<dim3(16, 16, 4), tb, 0, stream>>>(Wk, qkT + 262144, 512, 512, 262144, 524288);
    transpose_kernel<<<dim3(16, 16, 4), tb, 0, stream>>>(Wv, vT, 512, 512, 262144, 262144);
    transpose_kernel<<<dim3(16, 16, 4), tb, 0, stream>>>(Wo, oT, 512, 512, 262144, 262144);
    transpose_kernel<<<dim3(64, 16, 4), tb, 0, stream>>>(fc1c_W, fc1cT, 512, 2048, 1048576, 1048576);
    transpose_kernel<<<dim3(16, 64, 4), tb, 0, stream>>>(fc2c_W, fc2cT, 2048, 512, 1048576, 1048576);
    transpose_kernel<<<dim3(64, 16, 4), tb, 0, stream>>>(fc1v_W, fc1vT, 512, 2048, 1048576, 1048576);
    transpose_kernel<<<dim3(16, 64, 4), tb, 0, stream>>>(fc2v_W, fc2vT, 2048, 512, 1048576, 1048576);
    transpose_kernel<<<dim3(64, 48, 1), tb, 0, stream>>>(hW1, hW1T, 1536, 2048, 0, 0);
    transpose_kernel<<<dim3(8, 64, 1),  tb, 0, stream>>>(hW2, hW2T, 2048, 256, 0, 0);

    embed_kernel<<<TOK, 256, 0, stream>>>(q, r, ctx_emb, val_emb, pos_emb,
                                          ctx32, val32, ctx16, val16);

    for (int i = 0; i < NBLK; ++i) {
        mfma_gemm<128, true><<<dim3(8, 64), 256, 0, stream>>>(
            (const ushort*)ctx16, (const ushort*)(qkT + (size_t)i * 524288),
            bq + i * DM, bk + i * DM, 512, qk16, 1024, 512, 0, 0,
            nullptr, nullptr, nullptr, nullptr);
        mfma_gemm<64, true><<<dim3(8, 64), 256, 0, stream>>>(
            (const ushort*)val16, (const ushort*)(vT + (size_t)i * 262144),
            bv + i * DM, nullptr, 1 << 30, vt16, 512, 512, 0, 1,
            nullptr, nullptr, nullptr, nullptr);
        attn_kernel<<<dim3(16, 64), 256, 0, stream>>>(qk16, vt16, att16);
        mfma_gemm<64, true><<<dim3(8, 64), 256, 0, stream>>>(
            (const ushort*)att16, (const ushort*)(oT + (size_t)i * 262144),
            bo + i * DM, nullptr, 1 << 30, ob16c, 512, 512, 0, 0,
            nullptr, nullptr, nullptr, nullptr);
        lnp_kernel<<<dim3(TOK, 2), 256, 0, stream>>>(
            ctx32, ob16c, ln1c_s + i * DM, ln1c_b + i * DM, ctx32, ctx16,
            val32, ob16c, ln1v_s + i * DM, ln1v_b + i * DM, val32, val16);
        mfma_gemm<128, true><<<dim3(16, 64, 2), 256, 0, stream>>>(
            (const ushort*)ctx16, (const ushort*)(fc1cT + (size_t)i * 1048576),
            fc1c_b + i * DFFN, nullptr, 1 << 30, mid16c, 2048, 512, 1, 0,
            (const ushort*)val16, (const ushort*)(fc1vT + (size_t)i * 1048576),
            fc1v_b + i * DFFN, mid16v);
        mfma_gemm<128, true><<<dim3(4, 64, 2), 256, 0, stream>>>(
            (const ushort*)mid16c, (const ushort*)(fc2cT + (size_t)i * 1048576),
            fc2c_b + i * DM, nullptr, 1 << 30, ob16c, 512, 2048, 0, 0,
            (const ushort*)mid16v, (const ushort*)(fc2vT + (size_t)i * 1048576),
            fc2v_b + i * DM, ob16v);
        lnp_kernel<<<dim3(TOK, 2), 256, 0, stream>>>(
            ctx32, ob16c, ln2c_s + i * DM, ln2c_b + i * DM, ctx32, ctx16,
            val32, ob16v, ln2v_s + i * DM, ln2v_b + i * DM, val32, val16);
    }

    gather_kernel<<<TOK, 256, 0, stream>>>(ctx16, val16, skill_emb, q, feat16);
    mfma_gemm<128, true><<<dim3(16, 64), 256, 0, stream>>>(
        (const ushort*)feat16, (const ushort*)hW1T, hb1, nullptr, 1 << 30, mid16c, 2048, 1536, 1, 0,
        nullptr, nullptr, nullptr, nullptr);
    mfma_gemm<64, false><<<dim3(4, 64), 256, 0, stream>>>(
        (const ushort*)mid16c, (const ushort*)hW2T, hb2, nullptr, 1 << 30, h2, 256, 2048, 1, 0,
        nullptr, nullptr, nullptr, nullptr);
    logits_kernel<<<TOK, 256, 0, stream>>>(h2, hW3, hb3, out);
}

// Round 5
// 1115.417 us; speedup vs baseline: 1.0728x; 1.0346x over previous
//
#include <hip/hip_runtime.h>
#include <hip/hip_bf16.h>
#include <math.h>

#define TOK 8192   // B*L
#define DM 512
#define NH 8
#define DKH 64
#define DFFN 2048
#define SEQ 1024
#define NBLK 4
#define NUMC 1000

typedef __attribute__((ext_vector_type(8))) short bf16x8;
typedef __attribute__((ext_vector_type(4))) float f32x4;
typedef __attribute__((ext_vector_type(4))) ushort u16x4;
typedef __hip_bfloat16 bf16;

__device__ __forceinline__ void gload_lds16(const ushort* g, ushort* l) {
    __builtin_amdgcn_global_load_lds(
        (const __attribute__((address_space(1))) void*)g,
        (__attribute__((address_space(3))) void*)l, 16, 0, 0);
}

// raw workgroup barrier WITHOUT the compiler's vmcnt(0)/lgkmcnt(0) drain;
// empty asm = compiler-level memory fence so LDS ops can't migrate across.
__device__ __forceinline__ void wgbar() {
    asm volatile("" ::: "memory");
    __builtin_amdgcn_s_barrier();
    asm volatile("" ::: "memory");
}

// ---------------------------------------------------------------- embed
__global__ __launch_bounds__(256) void embed_kernel(
    const int* __restrict__ q, const int* __restrict__ r,
    const float* __restrict__ ctx_emb, const float* __restrict__ val_emb,
    const float* __restrict__ pos_emb,
    float* __restrict__ ctx32, float* __restrict__ val32,
    bf16* __restrict__ ctx16, bf16* __restrict__ val16)
{
    const int t = blockIdx.x;
    const int inter = q[t] + NUMC * r[t];
    const int l = t & (SEQ - 1);
    const float* ce = ctx_emb + (size_t)inter * DM;
    const float* ve = val_emb + (size_t)inter * DM;
    const float* pe = pos_emb + (size_t)l * DM;
    const size_t o = (size_t)t * DM;
    for (int d = threadIdx.x; d < DM; d += 256) {
        float p = pe[d];
        float c = ce[d] + p;
        float v = ve[d] + p;
        ctx32[o + d] = c; val32[o + d] = v;
        ctx16[o + d] = __float2bfloat16(c);
        val16[o + d] = __float2bfloat16(v);
    }
}

// ---------------------------------------------------------------- transpose+cvt (weights)
__global__ __launch_bounds__(256) void transpose_kernel(
    const float* __restrict__ src, bf16* __restrict__ dst,
    int K, int N, long sb, long db)
{
    __shared__ float t[32][33];
    src += (long)blockIdx.z * sb;
    dst += (long)blockIdx.z * db;
    const int n0 = blockIdx.x * 32;
    const int k0 = blockIdx.y * 32;
    const int tx = threadIdx.x;
    const int ty = threadIdx.y;
    for (int i = ty; i < 32; i += 8) t[i][tx] = src[(size_t)(k0 + i) * N + n0 + tx];
    __syncthreads();
    for (int i = ty; i < 32; i += 8)
        dst[(size_t)(n0 + i) * K + k0 + tx] = __float2bfloat16(t[tx][i]);
}

// ---------------------------------------------------------------- MFMA GEMM (128-tile, R5 structure)
template<int BN, bool OUTBF16>
__global__ __launch_bounds__(256, 3) void mfma_gemm(
    const ushort* __restrict__ A, const ushort* __restrict__ Bt,
    const float* __restrict__ bias1, const float* __restrict__ bias2, int split,
    void* __restrict__ Cv, int N, int K, int relu, int vtmode,
    const ushort* __restrict__ A1, const ushort* __restrict__ Bt1,
    const float* __restrict__ bias1_1, void* __restrict__ Cv1)
{
    if (blockIdx.z) { A = A1; Bt = Bt1; bias1 = bias1_1; Cv = Cv1; }
    constexpr int MI = (BN == 128) ? 4 : 2;
    constexpr int BR = BN / 32;
    __shared__ ushort As[128 * 64];
    __shared__ ushort Bs[BN * 64];
    const int tid = threadIdx.x;
    const int wave = tid >> 6;
    const int lane = tid & 63;
    const int ln = lane & 15;
    const int kq = lane >> 4;
    const int nx = gridDim.x;
    const int lin = blockIdx.x + nx * blockIdx.y;
    const int loc = lin >> 3;
    const int mdiv = loc / nx;
    const int bm = ((lin & 7) + 8 * mdiv) * 128;
    const int bn = (loc - mdiv * nx) * BN;
    const int wr = (BN == 128) ? (wave >> 1) * 64 : wave * 32;
    const int wc = (BN == 128) ? (wave & 1) * 64 : 0;

    const int trow = tid >> 3;
    const int gcb = (tid & 7) ^ (trow & 7);
    const ushort* Ab = A + (size_t)(bm + trow) * K + gcb * 8;
    const ushort* Bb = Bt + (size_t)(bn + trow) * K + gcb * 8;
    ushort* AsW = As + wave * 512;
    ushort* BsW = Bs + wave * 512;

    f32x4 acc[MI][4];
#pragma unroll
    for (int i = 0; i < MI; ++i)
#pragma unroll
        for (int j = 0; j < 4; ++j) acc[i][j] = (f32x4){0.f, 0.f, 0.f, 0.f};

    for (int k0 = 0; k0 < K; k0 += 64) {
        __syncthreads();
#pragma unroll
        for (int p = 0; p < 4; ++p)
            gload_lds16(Ab + (size_t)32 * p * K + k0, AsW + p * 2048);
#pragma unroll
        for (int p = 0; p < BR; ++p)
            gload_lds16(Bb + (size_t)32 * p * K + k0, BsW + p * 2048);
        __syncthreads();
#pragma unroll
        for (int half = 0; half < 2; ++half) {
            const int cb = ((half * 4 + kq) ^ (ln & 7)) * 8;
            bf16x8 bfr[4];
#pragma unroll
            for (int j = 0; j < 4; ++j)
                bfr[j] = *(const bf16x8*)&Bs[(wc + j * 16 + ln) * 64 + cb];
#pragma unroll
            for (int i = 0; i < MI; ++i) {
                const bf16x8 af = *(const bf16x8*)&As[(wr + i * 16 + ln) * 64 + cb];
#pragma unroll
                for (int j = 0; j < 4; ++j)
                    acc[i][j] = __builtin_amdgcn_mfma_f32_16x16x32_bf16(af, bfr[j], acc[i][j], 0, 0, 0);
            }
        }
    }

#pragma unroll
    for (int i = 0; i < MI; ++i) {
        const int rowb = bm + wr + i * 16 + kq * 4;
#pragma unroll
        for (int j = 0; j < 4; ++j) {
            const int colg = bn + wc + j * 16 + ln;
            const float bv = (colg < split) ? bias1[colg] : bias2[colg - split];
            if (vtmode) {
                union { u16x4 v; ushort u[4]; } pk;
#pragma unroll
                for (int rr = 0; rr < 4; ++rr) {
                    float v = acc[i][j][rr] + bv;
                    bf16 t = __float2bfloat16(v);
                    pk.u[rr] = *(ushort*)&t;
                }
                *(u16x4*)((ushort*)Cv + ((size_t)(rowb >> 10) * 512 + colg) * 1024 + (rowb & 1023)) = pk.v;
            } else {
#pragma unroll
                for (int rr = 0; rr < 4; ++rr) {
                    float v = acc[i][j][rr] + bv;
                    if (relu) v = fmaxf(v, 0.f);
                    if (OUTBF16)
                        ((bf16*)Cv)[(size_t)(rowb + rr) * N + colg] = __float2bfloat16(v);
                    else
                        ((float*)Cv)[(size_t)(rowb + rr) * N + colg] = v;
                }
            }
        }
    }
}

// ---------------------------------------------------------------- MFMA flash attention
// Counted-vmcnt pipeline at FULL occupancy (4 blocks/CU, LDS = 40960 B exactly):
//   Q 8KB + K double-buffer 16KB + V single-buffer 8KB + Ps 8KB (XOR-swizzled,
//   pad removed). Per kt:
//     barA (WAR: Vs & Ks[b^1] free) -> issue V(kt)->Vs, K(kt+1)->Ks[b^1]
//     vmcnt(4): K(kt) (issued one full iteration ago) landed; V(kt)+K(kt+1) in flight
//     barB (publish K) -> QK^T + softmax (slack covers V's L2 latency)
//     vmcnt(2): V(kt) landed -> barC (publish V) -> PV
//   Boundary waits (per-wave ledger, exact): kt=0: K-wait 2 (or 0 if qt==0);
//   kt==qt: K-wait 2, V-wait 0. Never drains prefetches mid-loop.
// Ps swizzle: elem (row,col=blk*8+off) stored at row*64 + (blk^(row&7))*8 + off;
// ap0/ap1 reads stay 16B-contiguous, <=2-way bank aliasing (free). Compute order
// identical to R0 -> bit-identical output.
__global__ __launch_bounds__(256) void attn_kernel(
    const bf16* __restrict__ QK, const bf16* __restrict__ Vt,
    bf16* __restrict__ Og)
{
    __shared__ ushort Qs[64 * 64];        // 8192 B
    __shared__ ushort Ks[2][64 * 64];     // 16384 B
    __shared__ ushort Vs[64 * 64];        // 8192 B  [dim][key]
    __shared__ ushort Ps[4 * 16 * 64];    // 8192 B  per-wave P, XOR-swizzled

    const int tid = threadIdx.x;
    const int wave = tid >> 6, lane = tid & 63;
    const int ln = lane & 15, kq = lane >> 4;
    const int lin = blockIdx.x + 16 * blockIdx.y;
    const int loc = lin >> 3;
    const int qt = loc & 15;
    const int bh = (lin & 7) + 8 * (loc >> 4);
    const int b = bh >> 3, h = bh & 7;

    const int srow = tid >> 3;                 // 0..31
    const int sgcb = (tid & 7) ^ (srow & 7);
    const ushort* gQ = (const ushort*)QK + (size_t)(b * SEQ + qt * 64 + srow) * 1024 + h * 64 + sgcb * 8;
    const ushort* gK = (const ushort*)QK + (size_t)(b * SEQ + srow) * 1024 + 512 + h * 64 + sgcb * 8;
    const ushort* gV = (const ushort*)Vt + (size_t)(bh * 64 + srow) * 1024 + sgcb * 8;

    // prologue issue order matters for the vmcnt ledger: Q2, V(0)2, K(0)2
    gload_lds16(gQ, Qs + wave * 512);
    gload_lds16(gQ + 32 * 1024, Qs + 2048 + wave * 512);
    gload_lds16(gV, Vs + wave * 512);
    gload_lds16(gV + (size_t)32 * 1024, Vs + 2048 + wave * 512);
    gload_lds16(gK, Ks[0] + wave * 512);
    gload_lds16(gK + (size_t)32 * 1024, Ks[0] + 2048 + wave * 512);

    float rs[4];
    f32x4 oacc[4];
#pragma unroll
    for (int r = 0; r < 4; ++r) { rs[r] = 0.f; oacc[r] = (f32x4){0.f, 0.f, 0.f, 0.f}; }
    const float sc2 = 0.125f * 1.4426950408889634f;   // 1/sqrt(64) * log2(e)

    const int cb0 = (kq ^ (ln & 7)) * 8;
    const int cb1 = ((4 + kq) ^ (ln & 7)) * 8;

    for (int kt = 0; kt <= qt; ++kt) {
        const int bf = kt & 1;
        if (kt > 0) {
            wgbar();   // barA: all waves done reading Vs (PV kt-1) and Ks[bf^1] (QK^T kt-1)
            const size_t kn = (size_t)kt * 64;
            gload_lds16(gV + kn, Vs + wave * 512);
            gload_lds16(gV + (size_t)32 * 1024 + kn, Vs + 2048 + wave * 512);
        }
        if (kt < qt) {
            const size_t kn1 = (size_t)(kt + 1) * 64;
            gload_lds16(gK + kn1 * 1024, Ks[bf ^ 1] + wave * 512);
            gload_lds16(gK + (kn1 + 32) * 1024, Ks[bf ^ 1] + 2048 + wave * 512);
            if (kt == 0) asm volatile("s_waitcnt vmcnt(2)" ::: "memory");  // drains Q,V(0),K(0); K(1) in flight
            else         asm volatile("s_waitcnt vmcnt(4)" ::: "memory");  // drains K(kt); V(kt)+K(kt+1) in flight
        } else {
            if (kt == 0) asm volatile("s_waitcnt vmcnt(0)" ::: "memory");  // qt==0: drain all
            else         asm volatile("s_waitcnt vmcnt(2)" ::: "memory");  // drains K(qt); V(qt) in flight
        }
        wgbar();   // barB: publish K(kt) (and Q/V(0) at kt==0)

        // S = Q K^T : per wave 16x64
        const bf16x8 aq0 = *(const bf16x8*)&Qs[(wave * 16 + ln) * 64 + cb0];
        const bf16x8 aq1 = *(const bf16x8*)&Qs[(wave * 16 + ln) * 64 + cb1];
        f32x4 s[4];
        __builtin_amdgcn_s_setprio(1);
#pragma unroll
        for (int c = 0; c < 4; ++c) {
            const bf16x8 bk0 = *(const bf16x8*)&Ks[bf][(c * 16 + ln) * 64 + cb0];
            const bf16x8 bk1 = *(const bf16x8*)&Ks[bf][(c * 16 + ln) * 64 + cb1];
            s[c] = (f32x4){0.f, 0.f, 0.f, 0.f};
            s[c] = __builtin_amdgcn_mfma_f32_16x16x32_bf16(aq0, bk0, s[c], 0, 0, 0);
            s[c] = __builtin_amdgcn_mfma_f32_16x16x32_bf16(aq1, bk1, s[c], 0, 0, 0);
        }
        __builtin_amdgcn_s_setprio(0);
        // P = exp2(s*sc2) with causal mask on the diagonal tile; no max shift.
        // Swizzled store: row=kq*4+r, blk=(2c+(ln>>3))^(row&7), off=ln&7.
        if (kt == qt) {
#pragma unroll
            for (int c = 0; c < 4; ++c)
#pragma unroll
                for (int r = 0; r < 4; ++r) {
                    const int qg = wave * 16 + kq * 4 + r;
                    const int jg = c * 16 + ln;
                    const float pv = (jg <= qg) ? exp2f(s[c][r] * sc2) : 0.f;
                    rs[r] += pv;
                    const int prow = kq * 4 + r;
                    const int pblk = (2 * c + (ln >> 3)) ^ (prow & 7);
                    *(bf16*)&Ps[wave * 1024 + prow * 64 + pblk * 8 + (ln & 7)] = __float2bfloat16(pv);
                }
        } else {
#pragma unroll
            for (int c = 0; c < 4; ++c)
#pragma unroll
                for (int r = 0; r < 4; ++r) {
                    const float pv = exp2f(s[c][r] * sc2);
                    rs[r] += pv;
                    const int prow = kq * 4 + r;
                    const int pblk = (2 * c + (ln >> 3)) ^ (prow & 7);
                    *(bf16*)&Ps[wave * 1024 + prow * 64 + pblk * 8 + (ln & 7)] = __float2bfloat16(pv);
                }
        }
        // V-wait + publish
        if (kt < qt) asm volatile("s_waitcnt vmcnt(2)" ::: "memory");  // drains V(kt); K(kt+1) in flight
        else         asm volatile("s_waitcnt vmcnt(0)" ::: "memory");
        wgbar();   // barC: publish V(kt)

        // P V (P from LDS in A-layout, swizzled; same-wave RAW)
        const bf16x8 ap0 = *(const bf16x8*)&Ps[wave * 1024 + ln * 64 + ((kq ^ (ln & 7)) << 3)];
        const bf16x8 ap1 = *(const bf16x8*)&Ps[wave * 1024 + ln * 64 + (((4 + kq) ^ (ln & 7)) << 3)];
        __builtin_amdgcn_s_setprio(1);
#pragma unroll
        for (int c2 = 0; c2 < 4; ++c2) {
            const bf16x8 bv0 = *(const bf16x8*)&Vs[(c2 * 16 + ln) * 64 + cb0];
            const bf16x8 bv1 = *(const bf16x8*)&Vs[(c2 * 16 + ln) * 64 + cb1];
            oacc[c2] = __builtin_amdgcn_mfma_f32_16x16x32_bf16(ap0, bv0, oacc[c2], 0, 0, 0);
            oacc[c2] = __builtin_amdgcn_mfma_f32_16x16x32_bf16(ap1, bv1, oacc[c2], 0, 0, 0);
        }
        __builtin_amdgcn_s_setprio(0);
    }
    // single row-sum reduction at the end
    float inv[4];
#pragma unroll
    for (int r = 0; r < 4; ++r) {
        float v = rs[r];
        v += __shfl_xor(v, 1);
        v += __shfl_xor(v, 2);
        v += __shfl_xor(v, 4);
        v += __shfl_xor(v, 8);
        inv[r] = 1.f / v;
    }
#pragma unroll
    for (int c2 = 0; c2 < 4; ++c2)
#pragma unroll
        for (int r = 0; r < 4; ++r)
            Og[(size_t)(b * SEQ + qt * 64 + wave * 16 + kq * 4 + r) * 512 + h * 64 + c2 * 16 + ln]
                = __float2bfloat16(oacc[c2][r] * inv[r]);
}

// ---------------------------------------------------------------- layernorm pair
__global__ __launch_bounds__(256) void lnp_kernel(
    const float* __restrict__ x0, const bf16* __restrict__ r0, const float* __restrict__ s0,
    const float* __restrict__ b0, float* __restrict__ of0, bf16* __restrict__ oh0,
    const float* __restrict__ x1, const bf16* __restrict__ r1, const float* __restrict__ s1,
    const float* __restrict__ b1, float* __restrict__ of1, bf16* __restrict__ oh1)
{
    const float* x = x0; const bf16* res = r0; const float* s = s0; const float* bb = b0;
    float* of = of0; bf16* oh = oh0;
    if (blockIdx.y) { x = x1; res = r1; s = s1; bb = b1; of = of1; oh = oh1; }
    __shared__ float w1[4], w2[4];
    const size_t o = (size_t)blockIdx.x * DM;
    const int i0 = threadIdx.x, i1 = threadIdx.x + 256;
    const float v0 = x[o + i0] + __bfloat162float(res[o + i0]);
    const float v1 = x[o + i1] + __bfloat162float(res[o + i1]);
    float sum = v0 + v1;
#pragma unroll
    for (int off = 32; off; off >>= 1) sum += __shfl_down(sum, off);
    if ((threadIdx.x & 63) == 0) w1[threadIdx.x >> 6] = sum;
    __syncthreads();
    const float mu = (w1[0] + w1[1] + w1[2] + w1[3]) * (1.f / DM);
    const float d0 = v0 - mu, d1 = v1 - mu;
    float vs = d0 * d0 + d1 * d1;
#pragma unroll
    for (int off = 32; off; off >>= 1) vs += __shfl_down(vs, off);
    if ((threadIdx.x & 63) == 0) w2[threadIdx.x >> 6] = vs;
    __syncthreads();
    const float rstd = rsqrtf((w2[0] + w2[1] + w2[2] + w2[3]) * (1.f / DM) + 1e-5f);
    const float o0 = d0 * rstd * s[i0] + bb[i0];
    const float o1 = d1 * rstd * s[i1] + bb[i1];
    of[o + i0] = o0; of[o + i1] = o1;
    oh[o + i0] = __float2bfloat16(o0);
    oh[o + i1] = __float2bfloat16(o1);
}

// ---------------------------------------------------------------- head gather
__global__ __launch_bounds__(256) void gather_kernel(
    const bf16* __restrict__ ctx16, const bf16* __restrict__ val16,
    const float* __restrict__ skill, const int* __restrict__ q,
    bf16* __restrict__ feat)
{
    const int t = blockIdx.x;
    const float* sp = skill + (size_t)q[t] * DM;
    const bf16* cp = ctx16 + (size_t)t * DM;
    const bf16* vp = val16 + (size_t)t * DM;
    bf16* fp = feat + (size_t)t * (3 * DM);
    for (int d = threadIdx.x; d < DM; d += 256) {
        fp[d] = cp[d];
        fp[DM + d] = vp[d];
        fp[2 * DM + d] = __float2bfloat16(sp[d]);
    }
}

// ---------------------------------------------------------------- logits
__global__ __launch_bounds__(256) void logits_kernel(
    const float* __restrict__ h2, const float* __restrict__ w,
    const float* __restrict__ bptr, float* __restrict__ out)
{
    __shared__ float w1[4];
    const int t = blockIdx.x;
    float sum = h2[(size_t)t * 256 + threadIdx.x] * w[threadIdx.x];
#pragma unroll
    for (int off = 32; off; off >>= 1) sum += __shfl_down(sum, off);
    if ((threadIdx.x & 63) == 0) w1[threadIdx.x >> 6] = sum;
    __syncthreads();
    if (threadIdx.x == 0) {
        const float logit = w1[0] + w1[1] + w1[2] + w1[3] + bptr[0];
        out[t] = 1.f / (1.f + __expf(-logit));
    }
}

// ---------------------------------------------------------------- launch
extern "C" void kernel_launch(void* const* d_in, const int* in_sizes, int n_in,
                              void* d_out, int out_size, void* d_ws, size_t ws_size,
                              hipStream_t stream)
{
    const int*   q         = (const int*)d_in[0];
    const int*   r         = (const int*)d_in[1];
    const float* ctx_emb   = (const float*)d_in[2];
    const float* val_emb   = (const float*)d_in[3];
    const float* skill_emb = (const float*)d_in[4];
    const float* pos_emb   = (const float*)d_in[5];
    const float* Wq = (const float*)d_in[6];
    const float* bq = (const float*)d_in[7];
    const float* Wk = (const float*)d_in[8];
    const float* bk = (const float*)d_in[9];
    const float* Wv = (const float*)d_in[10];
    const float* bv = (const float*)d_in[11];
    const float* Wo = (const float*)d_in[12];
    const float* bo = (const float*)d_in[13];
    const float* ln1c_s = (const float*)d_in[14];
    const float* ln1c_b = (const float*)d_in[15];
    const float* ln1v_s = (const float*)d_in[16];
    const float* ln1v_b = (const float*)d_in[17];
    const float* ln2c_s = (const float*)d_in[18];
    const float* ln2c_b = (const float*)d_in[19];
    const float* ln2v_s = (const float*)d_in[20];
    const float* ln2v_b = (const float*)d_in[21];
    const float* fc1c_W = (const float*)d_in[22];
    const float* fc1c_b = (const float*)d_in[23];
    const float* fc2c_W = (const float*)d_in[24];
    const float* fc2c_b = (const float*)d_in[25];
    const float* fc1v_W = (const float*)d_in[26];
    const float* fc1v_b = (const float*)d_in[27];
    const float* fc2v_W = (const float*)d_in[28];
    const float* fc2v_b = (const float*)d_in[29];
    const float* hW1 = (const float*)d_in[30];
    const float* hb1 = (const float*)d_in[31];
    const float* hW2 = (const float*)d_in[32];
    const float* hb2 = (const float*)d_in[33];
    const float* hW3 = (const float*)d_in[34];
    const float* hb3 = (const float*)d_in[35];
    float* out = (float*)d_out;

    char* p = (char*)d_ws;
    auto alloc = [&](size_t bytes) { char* ret = p; p += bytes; return ret; };
    float* ctx32 = (float*)alloc(16777216);
    float* val32 = (float*)alloc(16777216);
    bf16*  ob16c = (bf16*)alloc(8388608);
    bf16*  ob16v = (bf16*)alloc(8388608);
    bf16*  ctx16 = (bf16*)alloc(8388608);
    bf16*  val16 = (bf16*)alloc(8388608);
    bf16*  qk16  = (bf16*)alloc(16777216);   // A: [8192][1024]
    bf16*  v16pad= (bf16*)alloc(8388608);    // B: dead (alias sizing)
    bf16*  vt16  = (bf16*)alloc(8388608);    // C: [(b*8+h)*64+d][1024]
    bf16*  att16 = (bf16*)alloc(8388608);    // D
    bf16*  mid16c = (bf16*)alloc(33554432);  // [8192][2048]
    bf16*  qkT   = (bf16*)alloc(4194304);
    bf16*  vT    = (bf16*)alloc(2097152);
    bf16*  oT    = (bf16*)alloc(2097152);
    bf16*  fc1cT = (bf16*)alloc(8388608);
    bf16*  fc2cT = (bf16*)alloc(8388608);
    bf16*  fc1vT = (bf16*)alloc(8388608);
    bf16*  fc2vT = (bf16*)alloc(8388608);
    bf16*  hW1T  = (bf16*)alloc(6291456);
    bf16*  hW2T  = (bf16*)alloc(1048576);
    (void)v16pad;
    // aliases (liveness-checked):
    bf16*  mid16v = qk16;                    // dead during FFN
    bf16*  feat16 = qk16;                    // post-loop
    float* h2     = (float*)vt16;            // post-loop

    const dim3 tb(32, 8);
    transpose_kernel<<<dim3(16, 16, 4), tb, 0, stream>>>(Wq, qkT,          512, 512, 262144, 524288);
    transpose_kernel<<<dim3(16, 16, 4), tb, 0, stream>>>(Wk, qkT + 262144, 512, 512, 262144, 524288);
    transpose_kernel<<<dim3(16, 16, 4), tb, 0, stream>>>(Wv, vT, 512, 512, 262144, 262144);
    transpose_kernel<<<dim3(16, 16, 4), tb, 0, stream>>>(Wo, oT, 512, 512, 262144, 262144);
    transpose_kernel<<<dim3(64, 16, 4), tb, 0, stream>>>(fc1c_W, fc1cT, 512, 2048, 1048576, 1048576);
    transpose_kernel<<<dim3(16, 64, 4), tb, 0, stream>>>(fc2c_W, fc2cT, 2048, 512, 1048576, 1048576);
    transpose_kernel<<<dim3(64, 16, 4), tb, 0, stream>>>(fc1v_W, fc1vT, 512, 2048, 1048576, 1048576);
    transpose_kernel<<<dim3(16, 64, 4), tb, 0, stream>>>(fc2v_W, fc2vT, 2048, 512, 1048576, 1048576);
    transpose_kernel<<<dim3(64, 48, 1), tb, 0, stream>>>(hW1, hW1T, 1536, 2048, 0, 0);
    transpose_kernel<<<dim3(8, 64, 1),  tb, 0, stream>>>(hW2, hW2T, 2048, 256, 0, 0);

    embed_kernel<<<TOK, 256, 0, stream>>>(q, r, ctx_emb, val_emb, pos_emb,
                                          ctx32, val32, ctx16, val16);

    for (int i = 0; i < NBLK; ++i) {
        mfma_gemm<128, true><<<dim3(8, 64), 256, 0, stream>>>(
            (const ushort*)ctx16, (const ushort*)(qkT + (size_t)i * 524288),
            bq + i * DM, bk + i * DM, 512, qk16, 1024, 512, 0, 0,
            nullptr, nullptr, nullptr, nullptr);
        mfma_gemm<64, true><<<dim3(8, 64), 256, 0, stream>>>(
            (const ushort*)val16, (const ushort*)(vT + (size_t)i * 262144),
            bv + i * DM, nullptr, 1 << 30, vt16, 512, 512, 0, 1,
            nullptr, nullptr, nullptr, nullptr);
        attn_kernel<<<dim3(16, 64), 256, 0, stream>>>(qk16, vt16, att16);
        mfma_gemm<64, true><<<dim3(8, 64), 256, 0, stream>>>(
            (const ushort*)att16, (const ushort*)(oT + (size_t)i * 262144),
            bo + i * DM, nullptr, 1 << 30, ob16c, 512, 512, 0, 0,
            nullptr, nullptr, nullptr, nullptr);
        lnp_kernel<<<dim3(TOK, 2), 256, 0, stream>>>(
            ctx32, ob16c, ln1c_s + i * DM, ln1c_b + i * DM, ctx32, ctx16,
            val32, ob16c, ln1v_s + i * DM, ln1v_b + i * DM, val32, val16);
        mfma_gemm<128, true><<<dim3(16, 64, 2), 256, 0, stream>>>(
            (const ushort*)ctx16, (const ushort*)(fc1cT + (size_t)i * 1048576),
            fc1c_b + i * DFFN, nullptr, 1 << 30, mid16c, 2048, 512, 1, 0,
            (const ushort*)val16, (const ushort*)(fc1vT + (size_t)i * 1048576),
            fc1v_b + i * DFFN, mid16v);
        mfma_gemm<128, true><<<dim3(4, 64, 2), 256, 0, stream>>>(
            (const ushort*)mid16c, (const ushort*)(fc2cT + (size_t)i * 1048576),
            fc2c_b + i * DM, nullptr, 1 << 30, ob16c, 512, 2048, 0, 0,
            (const ushort*)mid16v, (const ushort*)(fc2vT + (size_t)i * 1048576),
            fc2v_b + i * DM, ob16v);
        lnp_kernel<<<dim3(TOK, 2), 256, 0, stream>>>(
            ctx32, ob16c, ln2c_s + i * DM, ln2c_b + i * DM, ctx32, ctx16,
            val32, ob16v, ln2v_s + i * DM, ln2v_b + i * DM, val32, val16);
    }

    gather_kernel<<<TOK, 256, 0, stream>>>(ctx16, val16, skill_emb, q, feat16);
    mfma_gemm<128, true><<<dim3(16, 64), 256, 0, stream>>>(
        (const ushort*)feat16, (const ushort*)hW1T, hb1, nullptr, 1 << 30, mid16c, 2048, 1536, 1, 0,
        nullptr, nullptr, nullptr, nullptr);
    mfma_gemm<64, false><<<dim3(4, 64), 256, 0, stream>>>(
        (const ushort*)mid16c, (const ushort*)hW2T, hb2, nullptr, 1 << 30, h2, 256, 2048, 1, 0,
        nullptr, nullptr, nullptr, nullptr);
    logits_kernel<<<TOK, 256, 0, stream>>>(h2, hW3, hb3, out);
}

// Round 6
// 1088.682 us; speedup vs baseline: 1.0991x; 1.0246x over previous
//
#include <hip/hip_runtime.h>
#include <hip/hip_bf16.h>
#include <math.h>

#define TOK 8192   // B*L
#define DM 512
#define NH 8
#define DKH 64
#define DFFN 2048
#define SEQ 1024
#define NBLK 4
#define NUMC 1000

typedef __attribute__((ext_vector_type(8))) short bf16x8;
typedef __attribute__((ext_vector_type(4))) float f32x4;
typedef __attribute__((ext_vector_type(4))) ushort u16x4;
typedef __hip_bfloat16 bf16;

__device__ __forceinline__ void gload_lds16(const ushort* g, ushort* l) {
    __builtin_amdgcn_global_load_lds(
        (const __attribute__((address_space(1))) void*)g,
        (__attribute__((address_space(3))) void*)l, 16, 0, 0);
}

// raw workgroup barrier WITHOUT the compiler's vmcnt(0)/lgkmcnt(0) drain;
// empty asm = compiler-level memory fence so LDS ops can't migrate across.
__device__ __forceinline__ void wgbar() {
    asm volatile("" ::: "memory");
    __builtin_amdgcn_s_barrier();
    asm volatile("" ::: "memory");
}

__device__ __forceinline__ float bf2f(short u) {
    return __uint_as_float((unsigned)(unsigned short)u << 16);
}

// ---------------------------------------------------------------- embed (wave-per-token, vectorized)
__global__ __launch_bounds__(256) void embed_kernel(
    const int* __restrict__ q, const int* __restrict__ r,
    const float* __restrict__ ctx_emb, const float* __restrict__ val_emb,
    const float* __restrict__ pos_emb,
    float* __restrict__ ctx32, float* __restrict__ val32,
    bf16* __restrict__ ctx16, bf16* __restrict__ val16)
{
    const int wave = threadIdx.x >> 6, lane = threadIdx.x & 63;
    const int t = blockIdx.x * 4 + wave;
    const int inter = q[t] + NUMC * r[t];
    const int l = t & (SEQ - 1);
    const int d0 = lane * 8;
    const float* ce = ctx_emb + (size_t)inter * DM + d0;
    const float* ve = val_emb + (size_t)inter * DM + d0;
    const float* pe = pos_emb + (size_t)l * DM + d0;
    const size_t o = (size_t)t * DM + d0;
    float c[8], v[8];
#pragma unroll
    for (int j = 0; j < 8; j += 4) {
        const float4 pv = *(const float4*)&pe[j];
        const float4 cv = *(const float4*)&ce[j];
        const float4 vv = *(const float4*)&ve[j];
        c[j] = cv.x + pv.x; c[j+1] = cv.y + pv.y; c[j+2] = cv.z + pv.z; c[j+3] = cv.w + pv.w;
        v[j] = vv.x + pv.x; v[j+1] = vv.y + pv.y; v[j+2] = vv.z + pv.z; v[j+3] = vv.w + pv.w;
        *(float4*)&ctx32[o + j] = (float4){c[j], c[j+1], c[j+2], c[j+3]};
        *(float4*)&val32[o + j] = (float4){v[j], v[j+1], v[j+2], v[j+3]};
    }
    union { bf16x8 vv; ushort u[8]; } pc, pv2;
#pragma unroll
    for (int j = 0; j < 8; ++j) {
        bf16 tc = __float2bfloat16(c[j]); pc.u[j] = *(ushort*)&tc;
        bf16 tv = __float2bfloat16(v[j]); pv2.u[j] = *(ushort*)&tv;
    }
    *(bf16x8*)&ctx16[o] = pc.vv;
    *(bf16x8*)&val16[o] = pv2.vv;
}

// ---------------------------------------------------------------- transpose+cvt (weights)
__global__ __launch_bounds__(256) void transpose_kernel(
    const float* __restrict__ src, bf16* __restrict__ dst,
    int K, int N, long sb, long db)
{
    __shared__ float t[32][33];
    src += (long)blockIdx.z * sb;
    dst += (long)blockIdx.z * db;
    const int n0 = blockIdx.x * 32;
    const int k0 = blockIdx.y * 32;
    const int tx = threadIdx.x;
    const int ty = threadIdx.y;
    for (int i = ty; i < 32; i += 8) t[i][tx] = src[(size_t)(k0 + i) * N + n0 + tx];
    __syncthreads();
    for (int i = ty; i < 32; i += 8)
        dst[(size_t)(n0 + i) * K + k0 + tx] = __float2bfloat16(t[tx][i]);
}

// ---------------------------------------------------------------- MFMA GEMM (128-tile, R5 structure)
template<int BN, bool OUTBF16>
__global__ __launch_bounds__(256, 3) void mfma_gemm(
    const ushort* __restrict__ A, const ushort* __restrict__ Bt,
    const float* __restrict__ bias1, const float* __restrict__ bias2, int split,
    void* __restrict__ Cv, int N, int K, int relu, int vtmode,
    const ushort* __restrict__ A1, const ushort* __restrict__ Bt1,
    const float* __restrict__ bias1_1, void* __restrict__ Cv1)
{
    if (blockIdx.z) { A = A1; Bt = Bt1; bias1 = bias1_1; Cv = Cv1; }
    constexpr int MI = (BN == 128) ? 4 : 2;
    constexpr int BR = BN / 32;
    __shared__ ushort As[128 * 64];
    __shared__ ushort Bs[BN * 64];
    const int tid = threadIdx.x;
    const int wave = tid >> 6;
    const int lane = tid & 63;
    const int ln = lane & 15;
    const int kq = lane >> 4;
    const int nx = gridDim.x;
    const int lin = blockIdx.x + nx * blockIdx.y;
    const int loc = lin >> 3;
    const int mdiv = loc / nx;
    const int bm = ((lin & 7) + 8 * mdiv) * 128;
    const int bn = (loc - mdiv * nx) * BN;
    const int wr = (BN == 128) ? (wave >> 1) * 64 : wave * 32;
    const int wc = (BN == 128) ? (wave & 1) * 64 : 0;

    const int trow = tid >> 3;
    const int gcb = (tid & 7) ^ (trow & 7);
    const ushort* Ab = A + (size_t)(bm + trow) * K + gcb * 8;
    const ushort* Bb = Bt + (size_t)(bn + trow) * K + gcb * 8;
    ushort* AsW = As + wave * 512;
    ushort* BsW = Bs + wave * 512;

    f32x4 acc[MI][4];
#pragma unroll
    for (int i = 0; i < MI; ++i)
#pragma unroll
        for (int j = 0; j < 4; ++j) acc[i][j] = (f32x4){0.f, 0.f, 0.f, 0.f};

    for (int k0 = 0; k0 < K; k0 += 64) {
        __syncthreads();
#pragma unroll
        for (int p = 0; p < 4; ++p)
            gload_lds16(Ab + (size_t)32 * p * K + k0, AsW + p * 2048);
#pragma unroll
        for (int p = 0; p < BR; ++p)
            gload_lds16(Bb + (size_t)32 * p * K + k0, BsW + p * 2048);
        __syncthreads();
#pragma unroll
        for (int half = 0; half < 2; ++half) {
            const int cb = ((half * 4 + kq) ^ (ln & 7)) * 8;
            bf16x8 bfr[4];
#pragma unroll
            for (int j = 0; j < 4; ++j)
                bfr[j] = *(const bf16x8*)&Bs[(wc + j * 16 + ln) * 64 + cb];
#pragma unroll
            for (int i = 0; i < MI; ++i) {
                const bf16x8 af = *(const bf16x8*)&As[(wr + i * 16 + ln) * 64 + cb];
#pragma unroll
                for (int j = 0; j < 4; ++j)
                    acc[i][j] = __builtin_amdgcn_mfma_f32_16x16x32_bf16(af, bfr[j], acc[i][j], 0, 0, 0);
            }
        }
    }

#pragma unroll
    for (int i = 0; i < MI; ++i) {
        const int rowb = bm + wr + i * 16 + kq * 4;
#pragma unroll
        for (int j = 0; j < 4; ++j) {
            const int colg = bn + wc + j * 16 + ln;
            const float bv = (colg < split) ? bias1[colg] : bias2[colg - split];
            if (vtmode) {
                union { u16x4 v; ushort u[4]; } pk;
#pragma unroll
                for (int rr = 0; rr < 4; ++rr) {
                    float v = acc[i][j][rr] + bv;
                    bf16 t = __float2bfloat16(v);
                    pk.u[rr] = *(ushort*)&t;
                }
                *(u16x4*)((ushort*)Cv + ((size_t)(rowb >> 10) * 512 + colg) * 1024 + (rowb & 1023)) = pk.v;
            } else {
#pragma unroll
                for (int rr = 0; rr < 4; ++rr) {
                    float v = acc[i][j][rr] + bv;
                    if (relu) v = fmaxf(v, 0.f);
                    if (OUTBF16)
                        ((bf16*)Cv)[(size_t)(rowb + rr) * N + colg] = __float2bfloat16(v);
                    else
                        ((float*)Cv)[(size_t)(rowb + rr) * N + colg] = v;
                }
            }
        }
    }
}

// ---------------------------------------------------------------- MFMA flash attention
// (R5 structure: counted-vmcnt pipeline at 4 blocks/CU, LDS = 40960 B)
__global__ __launch_bounds__(256) void attn_kernel(
    const bf16* __restrict__ QK, const bf16* __restrict__ Vt,
    bf16* __restrict__ Og)
{
    __shared__ ushort Qs[64 * 64];        // 8192 B
    __shared__ ushort Ks[2][64 * 64];     // 16384 B
    __shared__ ushort Vs[64 * 64];        // 8192 B  [dim][key]
    __shared__ ushort Ps[4 * 16 * 64];    // 8192 B  per-wave P, XOR-swizzled

    const int tid = threadIdx.x;
    const int wave = tid >> 6, lane = tid & 63;
    const int ln = lane & 15, kq = lane >> 4;
    const int lin = blockIdx.x + 16 * blockIdx.y;
    const int loc = lin >> 3;
    const int qt = loc & 15;
    const int bh = (lin & 7) + 8 * (loc >> 4);
    const int b = bh >> 3, h = bh & 7;

    const int srow = tid >> 3;                 // 0..31
    const int sgcb = (tid & 7) ^ (srow & 7);
    const ushort* gQ = (const ushort*)QK + (size_t)(b * SEQ + qt * 64 + srow) * 1024 + h * 64 + sgcb * 8;
    const ushort* gK = (const ushort*)QK + (size_t)(b * SEQ + srow) * 1024 + 512 + h * 64 + sgcb * 8;
    const ushort* gV = (const ushort*)Vt + (size_t)(bh * 64 + srow) * 1024 + sgcb * 8;

    // prologue issue order matters for the vmcnt ledger: Q2, V(0)2, K(0)2
    gload_lds16(gQ, Qs + wave * 512);
    gload_lds16(gQ + 32 * 1024, Qs + 2048 + wave * 512);
    gload_lds16(gV, Vs + wave * 512);
    gload_lds16(gV + (size_t)32 * 1024, Vs + 2048 + wave * 512);
    gload_lds16(gK, Ks[0] + wave * 512);
    gload_lds16(gK + (size_t)32 * 1024, Ks[0] + 2048 + wave * 512);

    float rs[4];
    f32x4 oacc[4];
#pragma unroll
    for (int r = 0; r < 4; ++r) { rs[r] = 0.f; oacc[r] = (f32x4){0.f, 0.f, 0.f, 0.f}; }
    const float sc2 = 0.125f * 1.4426950408889634f;   // 1/sqrt(64) * log2(e)

    const int cb0 = (kq ^ (ln & 7)) * 8;
    const int cb1 = ((4 + kq) ^ (ln & 7)) * 8;

    for (int kt = 0; kt <= qt; ++kt) {
        const int bf = kt & 1;
        if (kt > 0) {
            wgbar();   // barA: all waves done reading Vs (PV kt-1) and Ks[bf^1] (QK^T kt-1)
            const size_t kn = (size_t)kt * 64;
            gload_lds16(gV + kn, Vs + wave * 512);
            gload_lds16(gV + (size_t)32 * 1024 + kn, Vs + 2048 + wave * 512);
        }
        if (kt < qt) {
            const size_t kn1 = (size_t)(kt + 1) * 64;
            gload_lds16(gK + kn1 * 1024, Ks[bf ^ 1] + wave * 512);
            gload_lds16(gK + (kn1 + 32) * 1024, Ks[bf ^ 1] + 2048 + wave * 512);
            if (kt == 0) asm volatile("s_waitcnt vmcnt(2)" ::: "memory");  // drains Q,V(0),K(0); K(1) in flight
            else         asm volatile("s_waitcnt vmcnt(4)" ::: "memory");  // drains K(kt); V(kt)+K(kt+1) in flight
        } else {
            if (kt == 0) asm volatile("s_waitcnt vmcnt(0)" ::: "memory");  // qt==0: drain all
            else         asm volatile("s_waitcnt vmcnt(2)" ::: "memory");  // drains K(qt); V(qt) in flight
        }
        wgbar();   // barB: publish K(kt) (and Q/V(0) at kt==0)

        // S = Q K^T : per wave 16x64
        const bf16x8 aq0 = *(const bf16x8*)&Qs[(wave * 16 + ln) * 64 + cb0];
        const bf16x8 aq1 = *(const bf16x8*)&Qs[(wave * 16 + ln) * 64 + cb1];
        f32x4 s[4];
        __builtin_amdgcn_s_setprio(1);
#pragma unroll
        for (int c = 0; c < 4; ++c) {
            const bf16x8 bk0 = *(const bf16x8*)&Ks[bf][(c * 16 + ln) * 64 + cb0];
            const bf16x8 bk1 = *(const bf16x8*)&Ks[bf][(c * 16 + ln) * 64 + cb1];
            s[c] = (f32x4){0.f, 0.f, 0.f, 0.f};
            s[c] = __builtin_amdgcn_mfma_f32_16x16x32_bf16(aq0, bk0, s[c], 0, 0, 0);
            s[c] = __builtin_amdgcn_mfma_f32_16x16x32_bf16(aq1, bk1, s[c], 0, 0, 0);
        }
        __builtin_amdgcn_s_setprio(0);
        // P = exp2(s*sc2) with causal mask on the diagonal tile; no max shift.
        // Swizzled store: row=kq*4+r, blk=(2c+(ln>>3))^(row&7), off=ln&7.
        if (kt == qt) {
#pragma unroll
            for (int c = 0; c < 4; ++c)
#pragma unroll
                for (int r = 0; r < 4; ++r) {
                    const int qg = wave * 16 + kq * 4 + r;
                    const int jg = c * 16 + ln;
                    const float pv = (jg <= qg) ? exp2f(s[c][r] * sc2) : 0.f;
                    rs[r] += pv;
                    const int prow = kq * 4 + r;
                    const int pblk = (2 * c + (ln >> 3)) ^ (prow & 7);
                    *(bf16*)&Ps[wave * 1024 + prow * 64 + pblk * 8 + (ln & 7)] = __float2bfloat16(pv);
                }
        } else {
#pragma unroll
            for (int c = 0; c < 4; ++c)
#pragma unroll
                for (int r = 0; r < 4; ++r) {
                    const float pv = exp2f(s[c][r] * sc2);
                    rs[r] += pv;
                    const int prow = kq * 4 + r;
                    const int pblk = (2 * c + (ln >> 3)) ^ (prow & 7);
                    *(bf16*)&Ps[wave * 1024 + prow * 64 + pblk * 8 + (ln & 7)] = __float2bfloat16(pv);
                }
        }
        // V-wait + publish
        if (kt < qt) asm volatile("s_waitcnt vmcnt(2)" ::: "memory");  // drains V(kt); K(kt+1) in flight
        else         asm volatile("s_waitcnt vmcnt(0)" ::: "memory");
        wgbar();   // barC: publish V(kt)

        // P V (P from LDS in A-layout, swizzled; same-wave RAW)
        const bf16x8 ap0 = *(const bf16x8*)&Ps[wave * 1024 + ln * 64 + ((kq ^ (ln & 7)) << 3)];
        const bf16x8 ap1 = *(const bf16x8*)&Ps[wave * 1024 + ln * 64 + (((4 + kq) ^ (ln & 7)) << 3)];
        __builtin_amdgcn_s_setprio(1);
#pragma unroll
        for (int c2 = 0; c2 < 4; ++c2) {
            const bf16x8 bv0 = *(const bf16x8*)&Vs[(c2 * 16 + ln) * 64 + cb0];
            const bf16x8 bv1 = *(const bf16x8*)&Vs[(c2 * 16 + ln) * 64 + cb1];
            oacc[c2] = __builtin_amdgcn_mfma_f32_16x16x32_bf16(ap0, bv0, oacc[c2], 0, 0, 0);
            oacc[c2] = __builtin_amdgcn_mfma_f32_16x16x32_bf16(ap1, bv1, oacc[c2], 0, 0, 0);
        }
        __builtin_amdgcn_s_setprio(0);
    }
    // single row-sum reduction at the end
    float inv[4];
#pragma unroll
    for (int r = 0; r < 4; ++r) {
        float v = rs[r];
        v += __shfl_xor(v, 1);
        v += __shfl_xor(v, 2);
        v += __shfl_xor(v, 4);
        v += __shfl_xor(v, 8);
        inv[r] = 1.f / v;
    }
#pragma unroll
    for (int c2 = 0; c2 < 4; ++c2)
#pragma unroll
        for (int r = 0; r < 4; ++r)
            Og[(size_t)(b * SEQ + qt * 64 + wave * 16 + kq * 4 + r) * 512 + h * 64 + c2 * 16 + ln]
                = __float2bfloat16(oacc[c2][r] * inv[r]);
}

// ---------------------------------------------------------------- layernorm pair (wave-per-row)
// 1 wave per row: lane owns 8 contiguous elems (2xfloat4 + bf16x8 loads),
// 6-step shfl_xor reduction over 64 lanes; no LDS, no __syncthreads.
__global__ __launch_bounds__(256) void lnp_kernel(
    const float* __restrict__ x0, const bf16* __restrict__ r0, const float* __restrict__ s0,
    const float* __restrict__ b0, float* __restrict__ of0, bf16* __restrict__ oh0,
    const float* __restrict__ x1, const bf16* __restrict__ r1, const float* __restrict__ s1,
    const float* __restrict__ b1, float* __restrict__ of1, bf16* __restrict__ oh1)
{
    const float* x = x0; const bf16* res = r0; const float* s = s0; const float* bb = b0;
    float* of = of0; bf16* oh = oh0;
    if (blockIdx.y) { x = x1; res = r1; s = s1; bb = b1; of = of1; oh = oh1; }
    const int wave = threadIdx.x >> 6, lane = threadIdx.x & 63;
    const int row = blockIdx.x * 4 + wave;
    const int d0 = lane * 8;
    const size_t o = (size_t)row * DM + d0;

    const float4 xa = *(const float4*)&x[o];
    const float4 xb = *(const float4*)&x[o + 4];
    const bf16x8 rv = *(const bf16x8*)&res[o];
    float v[8];
    v[0] = xa.x + bf2f(rv[0]); v[1] = xa.y + bf2f(rv[1]);
    v[2] = xa.z + bf2f(rv[2]); v[3] = xa.w + bf2f(rv[3]);
    v[4] = xb.x + bf2f(rv[4]); v[5] = xb.y + bf2f(rv[5]);
    v[6] = xb.z + bf2f(rv[6]); v[7] = xb.w + bf2f(rv[7]);

    float sum = 0.f;
#pragma unroll
    for (int j = 0; j < 8; ++j) sum += v[j];
#pragma unroll
    for (int off = 1; off <= 32; off <<= 1) sum += __shfl_xor(sum, off);
    const float mu = sum * (1.f / DM);

    float vs = 0.f;
#pragma unroll
    for (int j = 0; j < 8; ++j) { const float d = v[j] - mu; vs += d * d; }
#pragma unroll
    for (int off = 1; off <= 32; off <<= 1) vs += __shfl_xor(vs, off);
    const float rstd = rsqrtf(vs * (1.f / DM) + 1e-5f);

    const float4 sa = *(const float4*)&s[d0];
    const float4 sb = *(const float4*)&s[d0 + 4];
    const float4 ba = *(const float4*)&bb[d0];
    const float4 b4 = *(const float4*)&bb[d0 + 4];
    float ov[8];
    ov[0] = (v[0] - mu) * rstd * sa.x + ba.x;
    ov[1] = (v[1] - mu) * rstd * sa.y + ba.y;
    ov[2] = (v[2] - mu) * rstd * sa.z + ba.z;
    ov[3] = (v[3] - mu) * rstd * sa.w + ba.w;
    ov[4] = (v[4] - mu) * rstd * sb.x + b4.x;
    ov[5] = (v[5] - mu) * rstd * sb.y + b4.y;
    ov[6] = (v[6] - mu) * rstd * sb.z + b4.z;
    ov[7] = (v[7] - mu) * rstd * sb.w + b4.w;
    *(float4*)&of[o]     = (float4){ov[0], ov[1], ov[2], ov[3]};
    *(float4*)&of[o + 4] = (float4){ov[4], ov[5], ov[6], ov[7]};
    union { bf16x8 vv; ushort u[8]; } pk;
#pragma unroll
    for (int j = 0; j < 8; ++j) { bf16 t = __float2bfloat16(ov[j]); pk.u[j] = *(ushort*)&t; }
    *(bf16x8*)&oh[o] = pk.vv;
}

// ---------------------------------------------------------------- head gather (wave-per-token)
__global__ __launch_bounds__(256) void gather_kernel(
    const bf16* __restrict__ ctx16, const bf16* __restrict__ val16,
    const float* __restrict__ skill, const int* __restrict__ q,
    bf16* __restrict__ feat)
{
    const int wave = threadIdx.x >> 6, lane = threadIdx.x & 63;
    const int t = blockIdx.x * 4 + wave;
    const int d0 = lane * 8;
    const float* sp = skill + (size_t)q[t] * DM + d0;
    bf16* fp = feat + (size_t)t * (3 * DM);
    *(bf16x8*)&fp[d0]      = *(const bf16x8*)&ctx16[(size_t)t * DM + d0];
    *(bf16x8*)&fp[DM + d0] = *(const bf16x8*)&val16[(size_t)t * DM + d0];
    const float4 s4a = *(const float4*)&sp[0];
    const float4 s4b = *(const float4*)&sp[4];
    union { bf16x8 vv; ushort u[8]; } pk;
    const float sv[8] = {s4a.x, s4a.y, s4a.z, s4a.w, s4b.x, s4b.y, s4b.z, s4b.w};
#pragma unroll
    for (int j = 0; j < 8; ++j) { bf16 t2 = __float2bfloat16(sv[j]); pk.u[j] = *(ushort*)&t2; }
    *(bf16x8*)&fp[2 * DM + d0] = pk.vv;
}

// ---------------------------------------------------------------- logits (wave-per-token)
__global__ __launch_bounds__(256) void logits_kernel(
    const float* __restrict__ h2, const float* __restrict__ w,
    const float* __restrict__ bptr, float* __restrict__ out)
{
    const int wave = threadIdx.x >> 6, lane = threadIdx.x & 63;
    const int t = blockIdx.x * 4 + wave;
    const float4 hv = *(const float4*)&h2[(size_t)t * 256 + lane * 4];
    const float4 wv = *(const float4*)&w[lane * 4];
    float sum = hv.x * wv.x + hv.y * wv.y + hv.z * wv.z + hv.w * wv.w;
#pragma unroll
    for (int off = 1; off <= 32; off <<= 1) sum += __shfl_xor(sum, off);
    if (lane == 0) {
        const float logit = sum + bptr[0];
        out[t] = 1.f / (1.f + __expf(-logit));
    }
}

// ---------------------------------------------------------------- launch
extern "C" void kernel_launch(void* const* d_in, const int* in_sizes, int n_in,
                              void* d_out, int out_size, void* d_ws, size_t ws_size,
                              hipStream_t stream)
{
    const int*   q         = (const int*)d_in[0];
    const int*   r         = (const int*)d_in[1];
    const float* ctx_emb   = (const float*)d_in[2];
    const float* val_emb   = (const float*)d_in[3];
    const float* skill_emb = (const float*)d_in[4];
    const float* pos_emb   = (const float*)d_in[5];
    const float* Wq = (const float*)d_in[6];
    const float* bq = (const float*)d_in[7];
    const float* Wk = (const float*)d_in[8];
    const float* bk = (const float*)d_in[9];
    const float* Wv = (const float*)d_in[10];
    const float* bv = (const float*)d_in[11];
    const float* Wo = (const float*)d_in[12];
    const float* bo = (const float*)d_in[13];
    const float* ln1c_s = (const float*)d_in[14];
    const float* ln1c_b = (const float*)d_in[15];
    const float* ln1v_s = (const float*)d_in[16];
    const float* ln1v_b = (const float*)d_in[17];
    const float* ln2c_s = (const float*)d_in[18];
    const float* ln2c_b = (const float*)d_in[19];
    const float* ln2v_s = (const float*)d_in[20];
    const float* ln2v_b = (const float*)d_in[21];
    const float* fc1c_W = (const float*)d_in[22];
    const float* fc1c_b = (const float*)d_in[23];
    const float* fc2c_W = (const float*)d_in[24];
    const float* fc2c_b = (const float*)d_in[25];
    const float* fc1v_W = (const float*)d_in[26];
    const float* fc1v_b = (const float*)d_in[27];
    const float* fc2v_W = (const float*)d_in[28];
    const float* fc2v_b = (const float*)d_in[29];
    const float* hW1 = (const float*)d_in[30];
    const float* hb1 = (const float*)d_in[31];
    const float* hW2 = (const float*)d_in[32];
    const float* hb2 = (const float*)d_in[33];
    const float* hW3 = (const float*)d_in[34];
    const float* hb3 = (const float*)d_in[35];
    float* out = (float*)d_out;

    char* p = (char*)d_ws;
    auto alloc = [&](size_t bytes) { char* ret = p; p += bytes; return ret; };
    float* ctx32 = (float*)alloc(16777216);
    float* val32 = (float*)alloc(16777216);
    bf16*  ob16c = (bf16*)alloc(8388608);
    bf16*  ob16v = (bf16*)alloc(8388608);
    bf16*  ctx16 = (bf16*)alloc(8388608);
    bf16*  val16 = (bf16*)alloc(8388608);
    bf16*  qk16  = (bf16*)alloc(16777216);   // A: [8192][1024]
    bf16*  v16pad= (bf16*)alloc(8388608);    // B: dead (alias sizing)
    bf16*  vt16  = (bf16*)alloc(8388608);    // C: [(b*8+h)*64+d][1024]
    bf16*  att16 = (bf16*)alloc(8388608);    // D
    bf16*  mid16c = (bf16*)alloc(33554432);  // [8192][2048]
    bf16*  qkT   = (bf16*)alloc(4194304);
    bf16*  vT    = (bf16*)alloc(2097152);
    bf16*  oT    = (bf16*)alloc(2097152);
    bf16*  fc1cT = (bf16*)alloc(8388608);
    bf16*  fc2cT = (bf16*)alloc(8388608);
    bf16*  fc1vT = (bf16*)alloc(8388608);
    bf16*  fc2vT = (bf16*)alloc(8388608);
    bf16*  hW1T  = (bf16*)alloc(6291456);
    bf16*  hW2T  = (bf16*)alloc(1048576);
    (void)v16pad;
    // aliases (liveness-checked):
    bf16*  mid16v = qk16;                    // dead during FFN
    bf16*  feat16 = qk16;                    // post-loop
    float* h2     = (float*)vt16;            // post-loop

    const dim3 tb(32, 8);
    transpose_kernel<<<dim3(16, 16, 4), tb, 0, stream>>>(Wq, qkT,          512, 512, 262144, 524288);
    transpose_kernel<<<dim3(16, 16, 4), tb, 0, stream>>>(Wk, qkT + 262144, 512, 512, 262144, 524288);
    transpose_kernel<<<dim3(16, 16, 4), tb, 0, stream>>>(Wv, vT, 512, 512, 262144, 262144);
    transpose_kernel<<<dim3(16, 16, 4), tb, 0, stream>>>(Wo, oT, 512, 512, 262144, 262144);
    transpose_kernel<<<dim3(64, 16, 4), tb, 0, stream>>>(fc1c_W, fc1cT, 512, 2048, 1048576, 1048576);
    transpose_kernel<<<dim3(16, 64, 4), tb, 0, stream>>>(fc2c_W, fc2cT, 2048, 512, 1048576, 1048576);
    transpose_kernel<<<dim3(64, 16, 4), tb, 0, stream>>>(fc1v_W, fc1vT, 512, 2048, 1048576, 1048576);
    transpose_kernel<<<dim3(16, 64, 4), tb, 0, stream>>>(fc2v_W, fc2vT, 2048, 512, 1048576, 1048576);
    transpose_kernel<<<dim3(64, 48, 1), tb, 0, stream>>>(hW1, hW1T, 1536, 2048, 0, 0);
    transpose_kernel<<<dim3(8, 64, 1),  tb, 0, stream>>>(hW2, hW2T, 2048, 256, 0, 0);

    embed_kernel<<<TOK / 4, 256, 0, stream>>>(q, r, ctx_emb, val_emb, pos_emb,
                                              ctx32, val32, ctx16, val16);

    for (int i = 0; i < NBLK; ++i) {
        mfma_gemm<128, true><<<dim3(8, 64), 256, 0, stream>>>(
            (const ushort*)ctx16, (const ushort*)(qkT + (size_t)i * 524288),
            bq + i * DM, bk + i * DM, 512, qk16, 1024, 512, 0, 0,
            nullptr, nullptr, nullptr, nullptr);
        mfma_gemm<64, true><<<dim3(8, 64), 256, 0, stream>>>(
            (const ushort*)val16, (const ushort*)(vT + (size_t)i * 262144),
            bv + i * DM, nullptr, 1 << 30, vt16, 512, 512, 0, 1,
            nullptr, nullptr, nullptr, nullptr);
        attn_kernel<<<dim3(16, 64), 256, 0, stream>>>(qk16, vt16, att16);
        mfma_gemm<64, true><<<dim3(8, 64), 256, 0, stream>>>(
            (const ushort*)att16, (const ushort*)(oT + (size_t)i * 262144),
            bo + i * DM, nullptr, 1 << 30, ob16c, 512, 512, 0, 0,
            nullptr, nullptr, nullptr, nullptr);
        lnp_kernel<<<dim3(TOK / 4, 2), 256, 0, stream>>>(
            ctx32, ob16c, ln1c_s + i * DM, ln1c_b + i * DM, ctx32, ctx16,
            val32, ob16c, ln1v_s + i * DM, ln1v_b + i * DM, val32, val16);
        mfma_gemm<128, true><<<dim3(16, 64, 2), 256, 0, stream>>>(
            (const ushort*)ctx16, (const ushort*)(fc1cT + (size_t)i * 1048576),
            fc1c_b + i * DFFN, nullptr, 1 << 30, mid16c, 2048, 512, 1, 0,
            (const ushort*)val16, (const ushort*)(fc1vT + (size_t)i * 1048576),
            fc1v_b + i * DFFN, mid16v);
        mfma_gemm<128, true><<<dim3(4, 64, 2), 256, 0, stream>>>(
            (const ushort*)mid16c, (const ushort*)(fc2cT + (size_t)i * 1048576),
            fc2c_b + i * DM, nullptr, 1 << 30, ob16c, 512, 2048, 0, 0,
            (const ushort*)mid16v, (const ushort*)(fc2vT + (size_t)i * 1048576),
            fc2v_b + i * DM, ob16v);
        lnp_kernel<<<dim3(TOK / 4, 2), 256, 0, stream>>>(
            ctx32, ob16c, ln2c_s + i * DM, ln2c_b + i * DM, ctx32, ctx16,
            val32, ob16v, ln2v_s + i * DM, ln2v_b + i * DM, val32, val16);
    }

    gather_kernel<<<TOK / 4, 256, 0, stream>>>(ctx16, val16, skill_emb, q, feat16);
    mfma_gemm<128, true><<<dim3(16, 64), 256, 0, stream>>>(
        (const ushort*)feat16, (const ushort*)hW1T, hb1, nullptr, 1 << 30, mid16c, 2048, 1536, 1, 0,
        nullptr, nullptr, nullptr, nullptr);
    mfma_gemm<64, false><<<dim3(4, 64), 256, 0, stream>>>(
        (const ushort*)mid16c, (const ushort*)hW2T, hb2, nullptr, 1 << 30, h2, 256, 2048, 1, 0,
        nullptr, nullptr, nullptr, nullptr);
    logits_kernel<<<TOK / 4, 256, 0, stream>>>(h2, hW3, hb3, out);
}